// Round 1
// baseline (2077.072 us; speedup 1.0000x reference)
//
#include <hip/hip_runtime.h>
#include <math.h>

#define NN 50000
#define NE 800000
#define IN_F 20
#define HID 64
#define HEADS 4
#define HD 64
#define CH 32      // hidden//2
#define C1 32      // classifier hidden
#define OUTC 2

static __device__ __forceinline__ unsigned fmap(float f){
  unsigned u = __float_as_uint(f);
  return (u & 0x80000000u) ? ~u : (u | 0x80000000u);
}
static __device__ __forceinline__ float funmap(unsigned u){
  return __uint_as_float((u & 0x80000000u) ? (u & 0x7FFFFFFFu) : ~u);
}

__global__ void k_zero(float* __restrict__ p, int n){
  int i = blockIdx.x * 256 + threadIdx.x;
  if (i < n) p[i] = 0.f;
}

__global__ void k_fill_u32(unsigned* __restrict__ p, int n, unsigned v){
  int i = blockIdx.x * 256 + threadIdx.x;
  if (i < n) p[i] = v;
}

__global__ void k_deg(const int* __restrict__ dst, float* __restrict__ deg){
  int e = blockIdx.x * 256 + threadIdx.x;
  if (e < NE) atomicAdd(&deg[dst[e]], 1.f);
}

// segment_sum(x[src], dst) into aggx [NN, IN_F]
__global__ void k_aggx(const int* __restrict__ src, const int* __restrict__ dst,
                       const float* __restrict__ x, float* __restrict__ aggx){
  int e = blockIdx.x * 256 + threadIdx.x;
  if (e >= NE) return;
  int s = src[e], d = dst[e];
  const float* xs = x + s * IN_F;
  float* ad = aggx + d * IN_F;
  #pragma unroll
  for (int k = 0; k < IN_F; k++) atomicAdd(&ad[k], xs[k]);
}

// h1 = relu(bn1(aggx/deg @ Wl1 + x @ Wr1 + b1)); thread per (n, j)
__global__ void k_sage1(const float* __restrict__ x, const float* __restrict__ aggx,
                        const float* __restrict__ deg,
                        const float* __restrict__ Wl, const float* __restrict__ Wr,
                        const float* __restrict__ b, const float* __restrict__ g,
                        const float* __restrict__ bt, float* __restrict__ h1){
  __shared__ float sWl[IN_F * HID], sWr[IN_F * HID];
  for (int i = threadIdx.x; i < IN_F * HID; i += 256) { sWl[i] = Wl[i]; sWr[i] = Wr[i]; }
  __syncthreads();
  int idx = blockIdx.x * 256 + threadIdx.x;
  if (idx >= NN * HID) return;
  int n = idx >> 6, j = idx & 63;
  float inv = 1.f / fmaxf(deg[n], 1.f);
  const float* xr = x + n * IN_F;
  const float* ar = aggx + n * IN_F;
  float acc = b[j];
  #pragma unroll
  for (int k = 0; k < IN_F; k++)
    acc += (ar[k] * inv) * sWl[k * HID + j] + xr[k] * sWr[k * HID + j];
  acc = acc * (g[j] * rsqrtf(1.f + 1e-5f)) + bt[j];
  h1[idx] = fmaxf(acc, 0.f);
}

// hp = h1 @ W2 (64 -> 256); a_s/a_d head dot products. One node per 256-thread block.
__global__ void k_gat_proj(const float* __restrict__ h1, const float* __restrict__ W2,
                           const float* __restrict__ att_src, const float* __restrict__ att_dst,
                           float* __restrict__ hp, float* __restrict__ a_s, float* __restrict__ a_d){
  int n = blockIdx.x;
  int t = threadIdx.x;
  __shared__ float sh[HID];
  if (t < HID) sh[t] = h1[n * HID + t];
  __syncthreads();
  float acc = 0.f;
  #pragma unroll
  for (int k = 0; k < HID; k++) acc += sh[k] * W2[k * (HEADS * HD) + t];
  hp[n * (HEADS * HD) + t] = acc;
  int h = t >> 6, d = t & 63;
  float vs = acc * att_src[h * HD + d];
  float vd = acc * att_dst[h * HD + d];
  #pragma unroll
  for (int o = 32; o > 0; o >>= 1) { vs += __shfl_down(vs, o); vd += __shfl_down(vd, o); }
  if (d == 0) { a_s[n * HEADS + h] = vs; a_d[n * HEADS + h] = vd; }
}

// pass 1: segment max of e = leaky_relu(a_s[src]+a_d[dst]) via monotone-uint atomicMax
__global__ void k_edge_max(const int* __restrict__ src, const int* __restrict__ dst,
                           const float* __restrict__ a_s, const float* __restrict__ a_d,
                           unsigned* __restrict__ mmax){
  int e = blockIdx.x * 256 + threadIdx.x;
  if (e >= NE) return;
  int s = src[e], d = dst[e];
  #pragma unroll
  for (int h = 0; h < HEADS; h++) {
    float v = a_s[s * HEADS + h] + a_d[d * HEADS + h];
    v = v >= 0.f ? v : 0.2f * v;
    atomicMax(&mmax[d * HEADS + h], fmap(v));
  }
}

// pass 2: ex = exp(e - m[dst]); denom += ex; accum[dst] += hp[src] * ex.
// thread per (edge, d) with d in [0,64); each thread covers all 4 heads at lane d.
__global__ void k_edge_soft(const int* __restrict__ src, const int* __restrict__ dst,
                            const float* __restrict__ a_s, const float* __restrict__ a_d,
                            const unsigned* __restrict__ mmax, const float* __restrict__ hp,
                            float* __restrict__ denom, float* __restrict__ accum){
  int idx = blockIdx.x * 256 + threadIdx.x;
  if (idx >= NE * 64) return;
  int e = idx >> 6, d = idx & 63;
  int s = src[e], dn = dst[e];
  float ex[HEADS];
  #pragma unroll
  for (int h = 0; h < HEADS; h++) {
    float v = a_s[s * HEADS + h] + a_d[dn * HEADS + h];
    v = v >= 0.f ? v : 0.2f * v;
    float m = funmap(mmax[dn * HEADS + h]);
    ex[h] = expf(v - m);
  }
  if (d < HEADS) atomicAdd(&denom[dn * HEADS + d], ex[d]);
  const float* hs = hp + s * (HEADS * HD);
  float* ac = accum + dn * (HEADS * HD);
  #pragma unroll
  for (int h = 0; h < HEADS; h++)
    atomicAdd(&ac[h * HD + d], hs[h * HD + d] * ex[h]);
}

// h2 = relu(bn2(mean_h(accum/denom) + b2))
__global__ void k_gat_fin(const float* __restrict__ accum, const float* __restrict__ denom,
                          const float* __restrict__ b2, const float* __restrict__ g2,
                          const float* __restrict__ bt2, float* __restrict__ h2){
  int idx = blockIdx.x * 256 + threadIdx.x;
  if (idx >= NN * HID) return;
  int n = idx >> 6, d = idx & 63;
  float acc = 0.f;
  #pragma unroll
  for (int h = 0; h < HEADS; h++)
    acc += accum[n * (HEADS * HD) + h * HD + d] / (denom[n * HEADS + h] + 1e-16f);
  acc = acc * 0.25f + b2[d];
  acc = acc * (g2[d] * rsqrtf(1.f + 1e-5f)) + bt2[d];
  h2[idx] = fmaxf(acc, 0.f);
}

// agg3[dst] += h2[src]; thread per (edge, d)
__global__ void k_agg_h2(const int* __restrict__ src, const int* __restrict__ dst,
                         const float* __restrict__ h2, float* __restrict__ agg3){
  int idx = blockIdx.x * 256 + threadIdx.x;
  if (idx >= NE * 64) return;
  int e = idx >> 6, d = idx & 63;
  atomicAdd(&agg3[dst[e] * HID + d], h2[src[e] * HID + d]);
}

// h3 = relu(bn3(agg3/deg @ Wl3 + h2 @ Wr3 + b3)) + (x @ Wskip + bskip); thread per (n,j), j<32
__global__ void k_sage3(const float* __restrict__ x, const float* __restrict__ h2,
                        const float* __restrict__ agg3, const float* __restrict__ deg,
                        const float* __restrict__ Wl3, const float* __restrict__ Wr3,
                        const float* __restrict__ b3, const float* __restrict__ g3,
                        const float* __restrict__ bt3, const float* __restrict__ Wskip,
                        const float* __restrict__ bskip, float* __restrict__ h3){
  __shared__ float sWl[HID * CH], sWr[HID * CH], sWs[IN_F * CH];
  for (int i = threadIdx.x; i < HID * CH; i += 256) { sWl[i] = Wl3[i]; sWr[i] = Wr3[i]; }
  for (int i = threadIdx.x; i < IN_F * CH; i += 256) sWs[i] = Wskip[i];
  __syncthreads();
  int idx = blockIdx.x * 256 + threadIdx.x;
  if (idx >= NN * CH) return;
  int n = idx >> 5, j = idx & 31;
  float inv = 1.f / fmaxf(deg[n], 1.f);
  float acc = b3[j];
  const float* ar = agg3 + n * HID;
  const float* hr = h2 + n * HID;
  #pragma unroll
  for (int k = 0; k < HID; k++)
    acc += (ar[k] * inv) * sWl[k * CH + j] + hr[k] * sWr[k * CH + j];
  acc = acc * (g3[j] * rsqrtf(1.f + 1e-5f)) + bt3[j];
  acc = fmaxf(acc, 0.f);
  float idn = bskip[j];
  const float* xr = x + n * IN_F;
  #pragma unroll
  for (int k = 0; k < IN_F; k++) idn += xr[k] * sWs[k * CH + j];
  h3[idx] = acc + idn;
}

// logits = relu(h3 @ Wc1 + bc1) @ Wc2 + bc2; log_softmax over 2 cols. Thread per node.
__global__ void k_cls(const float* __restrict__ h3, const float* __restrict__ Wc1,
                      const float* __restrict__ bc1, const float* __restrict__ Wc2,
                      const float* __restrict__ bc2, float* __restrict__ out){
  __shared__ float sW1[C1 * C1], sW2[C1 * OUTC], sb1[C1], sb2[OUTC];
  for (int i = threadIdx.x; i < C1 * C1; i += 256) sW1[i] = Wc1[i];
  if (threadIdx.x < C1 * OUTC) sW2[threadIdx.x] = Wc2[threadIdx.x];
  if (threadIdx.x < C1) sb1[threadIdx.x] = bc1[threadIdx.x];
  if (threadIdx.x < OUTC) sb2[threadIdx.x] = bc2[threadIdx.x];
  __syncthreads();
  int n = blockIdx.x * 256 + threadIdx.x;
  if (n >= NN) return;
  float hrow[CH];
  #pragma unroll
  for (int j = 0; j < CH; j++) hrow[j] = h3[n * CH + j];
  float l0 = sb2[0], l1 = sb2[1];
  #pragma unroll
  for (int i = 0; i < C1; i++) {
    float c = sb1[i];
    #pragma unroll
    for (int j = 0; j < CH; j++) c += hrow[j] * sW1[j * C1 + i];
    c = fmaxf(c, 0.f);
    l0 += c * sW2[i * OUTC + 0];
    l1 += c * sW2[i * OUTC + 1];
  }
  float mx = fmaxf(l0, l1);
  float lse = mx + logf(expf(l0 - mx) + expf(l1 - mx));
  out[n * OUTC + 0] = l0 - lse;
  out[n * OUTC + 1] = l1 - lse;
}

extern "C" void kernel_launch(void* const* d_in, const int* in_sizes, int n_in,
                              void* d_out, int out_size, void* d_ws, size_t ws_size,
                              hipStream_t stream) {
  const float* x       = (const float*)d_in[0];
  const int*   ei      = (const int*)d_in[1];
  const float* Wl1     = (const float*)d_in[2];
  const float* Wr1     = (const float*)d_in[3];
  const float* b1      = (const float*)d_in[4];
  const float* g1      = (const float*)d_in[5];
  const float* bt1     = (const float*)d_in[6];
  const float* W2      = (const float*)d_in[7];
  const float* att_src = (const float*)d_in[8];
  const float* att_dst = (const float*)d_in[9];
  const float* b2      = (const float*)d_in[10];
  const float* g2      = (const float*)d_in[11];
  const float* bt2     = (const float*)d_in[12];
  const float* Wl3     = (const float*)d_in[13];
  const float* Wr3     = (const float*)d_in[14];
  const float* b3      = (const float*)d_in[15];
  const float* g3      = (const float*)d_in[16];
  const float* bt3     = (const float*)d_in[17];
  const float* Wskip   = (const float*)d_in[18];
  const float* bskip   = (const float*)d_in[19];
  const float* Wc1     = (const float*)d_in[20];
  const float* bc1     = (const float*)d_in[21];
  const float* Wc2     = (const float*)d_in[22];
  const float* bc2     = (const float*)d_in[23];
  float* out = (float*)d_out;

  const int* src = ei;
  const int* dst = ei + NE;

  float* ws = (float*)d_ws;
  size_t off = 0;
  auto alloc = [&](size_t nf) { size_t o = off; off += (nf + 63) & ~(size_t)63; return o; };
  // zero-init region (contiguous): deg, aggx, denom, accum, agg3
  size_t o_deg   = alloc(NN);
  size_t o_aggx  = alloc((size_t)NN * IN_F);
  size_t o_denom = alloc((size_t)NN * HEADS);
  size_t o_accum = alloc((size_t)NN * HEADS * HD);
  size_t o_agg3  = alloc((size_t)NN * HID);
  size_t zero_elems = off;  // everything so far gets zeroed
  size_t o_mmax  = alloc((size_t)NN * HEADS);
  size_t o_h1    = alloc((size_t)NN * HID);
  size_t o_hp    = alloc((size_t)NN * HEADS * HD);
  size_t o_as    = alloc((size_t)NN * HEADS);
  size_t o_ad    = alloc((size_t)NN * HEADS);
  size_t o_h2    = alloc((size_t)NN * HID);
  size_t o_h3    = alloc((size_t)NN * CH);
  (void)ws_size; (void)in_sizes; (void)n_in; (void)out_size;

  float* deg   = ws + o_deg;
  float* aggx  = ws + o_aggx;
  float* denom = ws + o_denom;
  float* accum = ws + o_accum;
  float* agg3  = ws + o_agg3;
  unsigned* mmax = (unsigned*)(ws + o_mmax);
  float* h1    = ws + o_h1;
  float* hp    = ws + o_hp;
  float* a_s   = ws + o_as;
  float* a_d   = ws + o_ad;
  float* h2    = ws + o_h2;
  float* h3    = ws + o_h3;

  auto nb = [](long long n) { return (int)((n + 255) / 256); };

  k_zero<<<nb((long long)zero_elems), 256, 0, stream>>>(ws, (int)zero_elems);
  k_fill_u32<<<nb(NN * HEADS), 256, 0, stream>>>(mmax, NN * HEADS, 0x007FFFFFu); // fmap(-inf)
  k_deg<<<nb(NE), 256, 0, stream>>>(dst, deg);
  k_aggx<<<nb(NE), 256, 0, stream>>>(src, dst, x, aggx);
  k_sage1<<<nb((long long)NN * HID), 256, 0, stream>>>(x, aggx, deg, Wl1, Wr1, b1, g1, bt1, h1);
  k_gat_proj<<<NN, 256, 0, stream>>>(h1, W2, att_src, att_dst, hp, a_s, a_d);
  k_edge_max<<<nb(NE), 256, 0, stream>>>(src, dst, a_s, a_d, mmax);
  k_edge_soft<<<nb((long long)NE * 64), 256, 0, stream>>>(src, dst, a_s, a_d, mmax, hp, denom, accum);
  k_gat_fin<<<nb((long long)NN * HID), 256, 0, stream>>>(accum, denom, b2, g2, bt2, h2);
  k_agg_h2<<<nb((long long)NE * 64), 256, 0, stream>>>(src, dst, h2, agg3);
  k_sage3<<<nb((long long)NN * CH), 256, 0, stream>>>(x, h2, agg3, deg, Wl3, Wr3, b3, g3, bt3, Wskip, bskip, h3);
  k_cls<<<nb(NN), 256, 0, stream>>>(h3, Wc1, bc1, Wc2, bc2, out);
}

// Round 2
// 525.908 us; speedup vs baseline: 3.9495x; 3.9495x over previous
//
#include <hip/hip_runtime.h>
#include <math.h>

#define NN 50000
#define NE 800000
#define IN_F 20
#define HID 64
#define HEADS 4
#define HD 64
#define CH 32      // hidden//2
#define C1 32      // classifier hidden
#define OUTC 2

__global__ void k_zero_i(int* __restrict__ p, int n){
  int i = blockIdx.x * 256 + threadIdx.x;
  if (i < n) p[i] = 0;
}

// count[d] = in-degree
__global__ void k_count(const int* __restrict__ dst, int* __restrict__ count){
  int e = blockIdx.x * 256 + threadIdx.x;
  if (e < NE) atomicAdd(&count[dst[e]], 1);
}

// per-block exclusive scan (256 elems); block sums out
__global__ void k_scan_block(const int* __restrict__ in, int* __restrict__ out,
                             int* __restrict__ bsum, int n){
  __shared__ int tmp[256];
  int g = blockIdx.x * 256 + threadIdx.x;
  int v = (g < n) ? in[g] : 0;
  tmp[threadIdx.x] = v;
  __syncthreads();
  for (int o = 1; o < 256; o <<= 1) {
    int t = ((int)threadIdx.x >= o) ? tmp[threadIdx.x - o] : 0;
    __syncthreads();
    tmp[threadIdx.x] += t;
    __syncthreads();
  }
  if (g < n) out[g] = tmp[threadIdx.x] - v;   // exclusive
  if (bsum && threadIdx.x == 255) bsum[blockIdx.x] = tmp[255];
}

__global__ void k_add_off(int* __restrict__ rowptr, const int* __restrict__ bsum_ex, int n){
  int g = blockIdx.x * 256 + threadIdx.x;
  if (g < n) rowptr[g] += bsum_ex[g >> 8];
  if (g == 0) rowptr[NN] = NE;
}

// col[rowptr[d] + slot] = src[e]
__global__ void k_scatter(const int* __restrict__ src, const int* __restrict__ dst,
                          const int* __restrict__ rowptr, int* __restrict__ cnt2,
                          int* __restrict__ col){
  int e = blockIdx.x * 256 + threadIdx.x;
  if (e >= NE) return;
  int d = dst[e];
  int p = rowptr[d] + atomicAdd(&cnt2[d], 1);
  col[p] = src[e];
}

// aggx[n,k] = sum over incoming edges of x[src,k]; thread per (n, k) with k padded to 32
__global__ void k_aggx_gather(const int* __restrict__ rowptr, const int* __restrict__ col,
                              const float* __restrict__ x, float* __restrict__ aggx){
  int idx = blockIdx.x * 256 + threadIdx.x;
  int n = idx >> 5, k = idx & 31;
  if (n >= NN || k >= IN_F) return;
  int r0 = rowptr[n], r1 = rowptr[n + 1];
  float acc = 0.f;
  for (int j = r0; j < r1; j++) acc += x[col[j] * IN_F + k];
  aggx[n * IN_F + k] = acc;
}

// h1 = relu(bn1(aggx/deg @ Wl1 + x @ Wr1 + b1)); thread per (n, j)
__global__ void k_sage1(const float* __restrict__ x, const float* __restrict__ aggx,
                        const int* __restrict__ count,
                        const float* __restrict__ Wl, const float* __restrict__ Wr,
                        const float* __restrict__ b, const float* __restrict__ g,
                        const float* __restrict__ bt, float* __restrict__ h1){
  __shared__ float sWl[IN_F * HID], sWr[IN_F * HID];
  for (int i = threadIdx.x; i < IN_F * HID; i += 256) { sWl[i] = Wl[i]; sWr[i] = Wr[i]; }
  __syncthreads();
  int idx = blockIdx.x * 256 + threadIdx.x;
  if (idx >= NN * HID) return;
  int n = idx >> 6, j = idx & 63;
  float inv = 1.f / fmaxf((float)count[n], 1.f);
  const float* xr = x + n * IN_F;
  const float* ar = aggx + n * IN_F;
  float acc = b[j];
  #pragma unroll
  for (int k = 0; k < IN_F; k++)
    acc += (ar[k] * inv) * sWl[k * HID + j] + xr[k] * sWr[k * HID + j];
  acc = acc * (g[j] * rsqrtf(1.f + 1e-5f)) + bt[j];
  h1[idx] = fmaxf(acc, 0.f);
}

// hp = h1 @ W2 (64 -> 256); a_s/a_d head dot products. One node per 256-thread block.
__global__ void k_gat_proj(const float* __restrict__ h1, const float* __restrict__ W2,
                           const float* __restrict__ att_src, const float* __restrict__ att_dst,
                           float* __restrict__ hp, float* __restrict__ a_s, float* __restrict__ a_d){
  int n = blockIdx.x;
  int t = threadIdx.x;
  __shared__ float sh[HID];
  if (t < HID) sh[t] = h1[n * HID + t];
  __syncthreads();
  float acc = 0.f;
  #pragma unroll
  for (int k = 0; k < HID; k++) acc += sh[k] * W2[k * (HEADS * HD) + t];
  hp[n * (HEADS * HD) + t] = acc;
  int h = t >> 6, d = t & 63;
  float vs = acc * att_src[h * HD + d];
  float vd = acc * att_dst[h * HD + d];
  #pragma unroll
  for (int o = 32; o > 0; o >>= 1) { vs += __shfl_down(vs, o); vd += __shfl_down(vd, o); }
  if (d == 0) { a_s[n * HEADS + h] = vs; a_d[n * HEADS + h] = vd; }
}

// Fused GAT segment softmax + weighted aggregation + mean-heads + bn + relu.
// One wave (64 lanes) per node; lane = feature d. Two passes over the node's edges.
__global__ void k_gat_fused(const int* __restrict__ rowptr, const int* __restrict__ col,
                            const float* __restrict__ a_s, const float* __restrict__ a_d,
                            const float* __restrict__ hp,
                            const float* __restrict__ b2, const float* __restrict__ g2,
                            const float* __restrict__ bt2, float* __restrict__ h2){
  int wid = threadIdx.x >> 6;
  int lane = threadIdx.x & 63;
  int n = blockIdx.x * 4 + wid;
  if (n >= NN) return;
  int r0 = rowptr[n], r1 = rowptr[n + 1];
  float ad0 = a_d[n * 4 + 0], ad1 = a_d[n * 4 + 1], ad2 = a_d[n * 4 + 2], ad3 = a_d[n * 4 + 3];

  // pass 1: per-head max over incoming edges (lane-parallel + butterfly reduce)
  float m0 = -INFINITY, m1 = -INFINITY, m2 = -INFINITY, m3 = -INFINITY;
  for (int j = r0 + lane; j < r1; j += 64) {
    int s = col[j];
    float e0 = a_s[s * 4 + 0] + ad0; e0 = e0 >= 0.f ? e0 : 0.2f * e0;
    float e1 = a_s[s * 4 + 1] + ad1; e1 = e1 >= 0.f ? e1 : 0.2f * e1;
    float e2 = a_s[s * 4 + 2] + ad2; e2 = e2 >= 0.f ? e2 : 0.2f * e2;
    float e3 = a_s[s * 4 + 3] + ad3; e3 = e3 >= 0.f ? e3 : 0.2f * e3;
    m0 = fmaxf(m0, e0); m1 = fmaxf(m1, e1); m2 = fmaxf(m2, e2); m3 = fmaxf(m3, e3);
  }
  #pragma unroll
  for (int o = 1; o < 64; o <<= 1) {
    m0 = fmaxf(m0, __shfl_xor(m0, o)); m1 = fmaxf(m1, __shfl_xor(m1, o));
    m2 = fmaxf(m2, __shfl_xor(m2, o)); m3 = fmaxf(m3, __shfl_xor(m3, o));
  }

  // pass 2: exp / denom / weighted accumulation (serial over edges, lane = d)
  float l0 = 0.f, l1 = 0.f, l2 = 0.f, l3 = 0.f;
  float ac0 = 0.f, ac1 = 0.f, ac2 = 0.f, ac3 = 0.f;
  for (int j = r0; j < r1; j++) {
    int s = col[j];
    float e0 = a_s[s * 4 + 0] + ad0; e0 = e0 >= 0.f ? e0 : 0.2f * e0;
    float e1 = a_s[s * 4 + 1] + ad1; e1 = e1 >= 0.f ? e1 : 0.2f * e1;
    float e2 = a_s[s * 4 + 2] + ad2; e2 = e2 >= 0.f ? e2 : 0.2f * e2;
    float e3 = a_s[s * 4 + 3] + ad3; e3 = e3 >= 0.f ? e3 : 0.2f * e3;
    float p0 = __expf(e0 - m0), p1 = __expf(e1 - m1), p2 = __expf(e2 - m2), p3 = __expf(e3 - m3);
    l0 += p0; l1 += p1; l2 += p2; l3 += p3;
    const float* hs = hp + s * (HEADS * HD);
    ac0 += p0 * hs[lane];
    ac1 += p1 * hs[64 + lane];
    ac2 += p2 * hs[128 + lane];
    ac3 += p3 * hs[192 + lane];
  }
  float r = ac0 / (l0 + 1e-16f) + ac1 / (l1 + 1e-16f) + ac2 / (l2 + 1e-16f) + ac3 / (l3 + 1e-16f);
  r = r * 0.25f + b2[lane];
  r = r * (g2[lane] * rsqrtf(1.f + 1e-5f)) + bt2[lane];
  h2[n * HID + lane] = fmaxf(r, 0.f);
}

// agg3[n,d] = sum over incoming edges of h2[src,d]; thread per (n, d)
__global__ void k_agg3_gather(const int* __restrict__ rowptr, const int* __restrict__ col,
                              const float* __restrict__ h2, float* __restrict__ agg3){
  int idx = blockIdx.x * 256 + threadIdx.x;
  int n = idx >> 6, d = idx & 63;
  if (n >= NN) return;
  int r0 = rowptr[n], r1 = rowptr[n + 1];
  float acc = 0.f;
  for (int j = r0; j < r1; j++) acc += h2[col[j] * HID + d];
  agg3[idx] = acc;
}

// h3 = relu(bn3(agg3/deg @ Wl3 + h2 @ Wr3 + b3)) + (x @ Wskip + bskip); thread per (n,j), j<32
__global__ void k_sage3(const float* __restrict__ x, const float* __restrict__ h2,
                        const float* __restrict__ agg3, const int* __restrict__ count,
                        const float* __restrict__ Wl3, const float* __restrict__ Wr3,
                        const float* __restrict__ b3, const float* __restrict__ g3,
                        const float* __restrict__ bt3, const float* __restrict__ Wskip,
                        const float* __restrict__ bskip, float* __restrict__ h3){
  __shared__ float sWl[HID * CH], sWr[HID * CH], sWs[IN_F * CH];
  for (int i = threadIdx.x; i < HID * CH; i += 256) { sWl[i] = Wl3[i]; sWr[i] = Wr3[i]; }
  for (int i = threadIdx.x; i < IN_F * CH; i += 256) sWs[i] = Wskip[i];
  __syncthreads();
  int idx = blockIdx.x * 256 + threadIdx.x;
  if (idx >= NN * CH) return;
  int n = idx >> 5, j = idx & 31;
  float inv = 1.f / fmaxf((float)count[n], 1.f);
  float acc = b3[j];
  const float* ar = agg3 + n * HID;
  const float* hr = h2 + n * HID;
  #pragma unroll
  for (int k = 0; k < HID; k++)
    acc += (ar[k] * inv) * sWl[k * CH + j] + hr[k] * sWr[k * CH + j];
  acc = acc * (g3[j] * rsqrtf(1.f + 1e-5f)) + bt3[j];
  acc = fmaxf(acc, 0.f);
  float idn = bskip[j];
  const float* xr = x + n * IN_F;
  #pragma unroll
  for (int k = 0; k < IN_F; k++) idn += xr[k] * sWs[k * CH + j];
  h3[idx] = acc + idn;
}

// logits = relu(h3 @ Wc1 + bc1) @ Wc2 + bc2; log_softmax over 2 cols. Thread per node.
__global__ void k_cls(const float* __restrict__ h3, const float* __restrict__ Wc1,
                      const float* __restrict__ bc1, const float* __restrict__ Wc2,
                      const float* __restrict__ bc2, float* __restrict__ out){
  __shared__ float sW1[C1 * C1], sW2[C1 * OUTC], sb1[C1], sb2[OUTC];
  for (int i = threadIdx.x; i < C1 * C1; i += 256) sW1[i] = Wc1[i];
  if (threadIdx.x < C1 * OUTC) sW2[threadIdx.x] = Wc2[threadIdx.x];
  if (threadIdx.x < C1) sb1[threadIdx.x] = bc1[threadIdx.x];
  if (threadIdx.x < OUTC) sb2[threadIdx.x] = bc2[threadIdx.x];
  __syncthreads();
  int n = blockIdx.x * 256 + threadIdx.x;
  if (n >= NN) return;
  float hrow[CH];
  #pragma unroll
  for (int j = 0; j < CH; j++) hrow[j] = h3[n * CH + j];
  float l0 = sb2[0], l1 = sb2[1];
  #pragma unroll
  for (int i = 0; i < C1; i++) {
    float c = sb1[i];
    #pragma unroll
    for (int j = 0; j < CH; j++) c += hrow[j] * sW1[j * C1 + i];
    c = fmaxf(c, 0.f);
    l0 += c * sW2[i * OUTC + 0];
    l1 += c * sW2[i * OUTC + 1];
  }
  float mx = fmaxf(l0, l1);
  float lse = mx + logf(expf(l0 - mx) + expf(l1 - mx));
  out[n * OUTC + 0] = l0 - lse;
  out[n * OUTC + 1] = l1 - lse;
}

extern "C" void kernel_launch(void* const* d_in, const int* in_sizes, int n_in,
                              void* d_out, int out_size, void* d_ws, size_t ws_size,
                              hipStream_t stream) {
  const float* x       = (const float*)d_in[0];
  const int*   ei      = (const int*)d_in[1];
  const float* Wl1     = (const float*)d_in[2];
  const float* Wr1     = (const float*)d_in[3];
  const float* b1      = (const float*)d_in[4];
  const float* g1      = (const float*)d_in[5];
  const float* bt1     = (const float*)d_in[6];
  const float* W2      = (const float*)d_in[7];
  const float* att_src = (const float*)d_in[8];
  const float* att_dst = (const float*)d_in[9];
  const float* b2      = (const float*)d_in[10];
  const float* g2      = (const float*)d_in[11];
  const float* bt2     = (const float*)d_in[12];
  const float* Wl3     = (const float*)d_in[13];
  const float* Wr3     = (const float*)d_in[14];
  const float* b3      = (const float*)d_in[15];
  const float* g3      = (const float*)d_in[16];
  const float* bt3     = (const float*)d_in[17];
  const float* Wskip   = (const float*)d_in[18];
  const float* bskip   = (const float*)d_in[19];
  const float* Wc1     = (const float*)d_in[20];
  const float* bc1     = (const float*)d_in[21];
  const float* Wc2     = (const float*)d_in[22];
  const float* bc2     = (const float*)d_in[23];
  float* out = (float*)d_out;

  const int* src = ei;
  const int* dst = ei + NE;

  float* ws = (float*)d_ws;
  size_t off = 0;
  auto alloc = [&](size_t nf) { size_t o = off; off += (nf + 63) & ~(size_t)63; return o; };
  // zero region (ints): count, cnt2 — contiguous
  size_t o_count = alloc(NN);
  size_t o_cnt2  = alloc(NN);
  size_t zero_elems = off;
  size_t o_rowptr = alloc(NN + 1);
  size_t o_bsum   = alloc(256);
  size_t o_bsumex = alloc(256);
  size_t o_col    = alloc(NE);
  size_t o_aggx   = alloc((size_t)NN * IN_F);
  size_t o_h1     = alloc((size_t)NN * HID);
  size_t o_hp     = alloc((size_t)NN * HEADS * HD);
  size_t o_as     = alloc((size_t)NN * HEADS);
  size_t o_ad     = alloc((size_t)NN * HEADS);
  size_t o_h2     = alloc((size_t)NN * HID);
  size_t o_agg3   = alloc((size_t)NN * HID);
  size_t o_h3     = alloc((size_t)NN * CH);
  (void)ws_size; (void)in_sizes; (void)n_in; (void)out_size;

  int* count   = (int*)(ws + o_count);
  int* cnt2    = (int*)(ws + o_cnt2);
  int* rowptr  = (int*)(ws + o_rowptr);
  int* bsum    = (int*)(ws + o_bsum);
  int* bsumex  = (int*)(ws + o_bsumex);
  int* col     = (int*)(ws + o_col);
  float* aggx  = ws + o_aggx;
  float* h1    = ws + o_h1;
  float* hp    = ws + o_hp;
  float* a_s   = ws + o_as;
  float* a_d   = ws + o_ad;
  float* h2    = ws + o_h2;
  float* agg3  = ws + o_agg3;
  float* h3    = ws + o_h3;

  auto nb = [](long long n) { return (int)((n + 255) / 256); };
  const int nscan = nb(NN);  // 196

  k_zero_i<<<nb((long long)zero_elems), 256, 0, stream>>>((int*)ws, (int)zero_elems);
  k_count<<<nb(NE), 256, 0, stream>>>(dst, count);
  k_scan_block<<<nscan, 256, 0, stream>>>(count, rowptr, bsum, NN);
  k_scan_block<<<1, 256, 0, stream>>>(bsum, bsumex, nullptr, nscan);
  k_add_off<<<nscan, 256, 0, stream>>>(rowptr, bsumex, NN);
  k_scatter<<<nb(NE), 256, 0, stream>>>(src, dst, rowptr, cnt2, col);
  k_aggx_gather<<<nb((long long)NN * 32), 256, 0, stream>>>(rowptr, col, x, aggx);
  k_sage1<<<nb((long long)NN * HID), 256, 0, stream>>>(x, aggx, count, Wl1, Wr1, b1, g1, bt1, h1);
  k_gat_proj<<<NN, 256, 0, stream>>>(h1, W2, att_src, att_dst, hp, a_s, a_d);
  k_gat_fused<<<nb((long long)NN * 64), 256, 0, stream>>>(rowptr, col, a_s, a_d, hp, b2, g2, bt2, h2);
  k_agg3_gather<<<nb((long long)NN * 64), 256, 0, stream>>>(rowptr, col, h2, agg3);
  k_sage3<<<nb((long long)NN * CH), 256, 0, stream>>>(x, h2, agg3, count, Wl3, Wr3, b3, g3, bt3, Wskip, bskip, h3);
  k_cls<<<nb(NN), 256, 0, stream>>>(h3, Wc1, bc1, Wc2, bc2, out);
}

// Round 3
// 446.206 us; speedup vs baseline: 4.6550x; 1.1786x over previous
//
#include <hip/hip_runtime.h>
#include <hip/hip_fp16.h>
#include <math.h>

#define NN 50000
#define NE 800000
#define IN_F 20
#define HID 64
#define HEADS 4
#define HD 64
#define CH 32      // hidden//2
#define C1 32      // classifier hidden
#define OUTC 2

__global__ void k_zero_i(int* __restrict__ p, int n){
  int i = blockIdx.x * 256 + threadIdx.x;
  if (i < n) p[i] = 0;
}

// count[d] = in-degree
__global__ void k_count(const int* __restrict__ dst, int* __restrict__ count){
  int e = blockIdx.x * 256 + threadIdx.x;
  if (e < NE) atomicAdd(&count[dst[e]], 1);
}

// per-block exclusive scan (256 elems); block sums out
__global__ void k_scan_block(const int* __restrict__ in, int* __restrict__ out,
                             int* __restrict__ bsum, int n){
  __shared__ int tmp[256];
  int g = blockIdx.x * 256 + threadIdx.x;
  int v = (g < n) ? in[g] : 0;
  tmp[threadIdx.x] = v;
  __syncthreads();
  for (int o = 1; o < 256; o <<= 1) {
    int t = ((int)threadIdx.x >= o) ? tmp[threadIdx.x - o] : 0;
    __syncthreads();
    tmp[threadIdx.x] += t;
    __syncthreads();
  }
  if (g < n) out[g] = tmp[threadIdx.x] - v;   // exclusive
  if (bsum && threadIdx.x == 255) bsum[blockIdx.x] = tmp[255];
}

__global__ void k_add_off(int* __restrict__ rowptr, const int* __restrict__ bsum_ex, int n){
  int g = blockIdx.x * 256 + threadIdx.x;
  if (g < n) rowptr[g] += bsum_ex[g >> 8];
  if (g == 0) rowptr[NN] = NE;
}

// col[rowptr[d] + slot] = src[e]
__global__ void k_scatter(const int* __restrict__ src, const int* __restrict__ dst,
                          const int* __restrict__ rowptr, int* __restrict__ cnt2,
                          int* __restrict__ col){
  int e = blockIdx.x * 256 + threadIdx.x;
  if (e >= NE) return;
  int d = dst[e];
  int p = rowptr[d] + atomicAdd(&cnt2[d], 1);
  col[p] = src[e];
}

// x -> fp16 copy
__global__ void k_xhalf(const float* __restrict__ x, __half* __restrict__ xh){
  int i = blockIdx.x * 256 + threadIdx.x;
  if (i < NN * IN_F) xh[i] = __float2half(x[i]);
}

// was[h][k] = sum_d W2[k, h*64+d]*att_src[h][d]; wad likewise. One block of 256.
__global__ void k_was(const float* __restrict__ W2, const float* __restrict__ att_src,
                      const float* __restrict__ att_dst,
                      float* __restrict__ was, float* __restrict__ wad){
  int t = threadIdx.x;          // t = h*64 + k
  int h = t >> 6, k = t & 63;
  float s = 0.f, dd = 0.f;
  for (int d = 0; d < 64; d++) {
    float w = W2[k * 256 + h * 64 + d];
    s  += w * att_src[h * 64 + d];
    dd += w * att_dst[h * 64 + d];
  }
  was[t] = s; wad[t] = dd;
}

// W2r[(h*64+k)*64 + d] = W2[k*256 + h*64 + d]
__global__ void k_w2r(const float* __restrict__ W2, float* __restrict__ W2r){
  int i = blockIdx.x * 256 + threadIdx.x;
  if (i >= 256 * 64) return;
  int hk = i >> 6, d = i & 63;
  int h = hk >> 6, k = hk & 63;
  W2r[i] = W2[k * 256 + h * 64 + d];
}

// aggx[n,k] = sum over incoming edges of xh[src,k]; thread per (n, k) with k padded to 32
__global__ void k_aggx_gather(const int* __restrict__ rowptr, const int* __restrict__ col,
                              const __half* __restrict__ xh, float* __restrict__ aggx){
  int idx = blockIdx.x * 256 + threadIdx.x;
  int n = idx >> 5, k = idx & 31;
  if (n >= NN || k >= IN_F) return;
  int r0 = rowptr[n], r1 = rowptr[n + 1];
  float acc = 0.f;
  for (int j = r0; j < r1; j++) acc += __half2float(xh[col[j] * IN_F + k]);
  aggx[n * IN_F + k] = acc;
}

// h1 = relu(bn1(aggx/deg @ Wl1 + x @ Wr1 + b1)); writes fp16 h1h + attention logits
__global__ void k_sage1(const float* __restrict__ x, const float* __restrict__ aggx,
                        const int* __restrict__ count,
                        const float* __restrict__ Wl, const float* __restrict__ Wr,
                        const float* __restrict__ b, const float* __restrict__ g,
                        const float* __restrict__ bt,
                        const float* __restrict__ was, const float* __restrict__ wad,
                        __half* __restrict__ h1h, float* __restrict__ a_s,
                        float* __restrict__ a_d){
  __shared__ float sWl[IN_F * HID], sWr[IN_F * HID], sWas[256], sWad[256];
  for (int i = threadIdx.x; i < IN_F * HID; i += 256) { sWl[i] = Wl[i]; sWr[i] = Wr[i]; }
  { int i = threadIdx.x; sWas[i] = was[i]; sWad[i] = wad[i]; }
  __syncthreads();
  int idx = blockIdx.x * 256 + threadIdx.x;
  if (idx >= NN * HID) return;
  int n = idx >> 6, j = idx & 63;
  float inv = 1.f / fmaxf((float)count[n], 1.f);
  const float* xr = x + n * IN_F;
  const float* ar = aggx + n * IN_F;
  float acc = b[j];
  #pragma unroll
  for (int k = 0; k < IN_F; k++)
    acc += (ar[k] * inv) * sWl[k * HID + j] + xr[k] * sWr[k * HID + j];
  acc = acc * (g[j] * rsqrtf(1.f + 1e-5f)) + bt[j];
  acc = fmaxf(acc, 0.f);
  h1h[idx] = __float2half(acc);
  #pragma unroll
  for (int h = 0; h < HEADS; h++) {
    float vs = acc * sWas[h * 64 + j];
    float vd = acc * sWad[h * 64 + j];
    #pragma unroll
    for (int o = 32; o > 0; o >>= 1) { vs += __shfl_down(vs, o); vd += __shfl_down(vd, o); }
    if (j == 0) { a_s[n * 4 + h] = vs; a_d[n * 4 + h] = vd; }
  }
}

// Fused GAT: per node (one wave, lane = h1 feature k), single pass over edges.
// z'[n, h*64+k] = (sum_e exp(e_h) * h1[src][k]) / (4*(sum_e exp(e_h) + 1e-16))
__global__ void k_gat_fused(const int* __restrict__ rowptr, const int* __restrict__ col,
                            const float4* __restrict__ a_s4, const float4* __restrict__ a_d4,
                            const __half* __restrict__ h1h, float* __restrict__ z){
  int wid = threadIdx.x >> 6;
  int lane = threadIdx.x & 63;
  int n = blockIdx.x * 4 + wid;
  if (n >= NN) return;
  int r0 = rowptr[n], r1 = rowptr[n + 1];
  float4 ad = a_d4[n];
  float l0 = 0.f, l1 = 0.f, l2 = 0.f, l3 = 0.f;
  float ac0 = 0.f, ac1 = 0.f, ac2 = 0.f, ac3 = 0.f;
  for (int j = r0; j < r1; j++) {
    int s = col[j];
    float4 as = a_s4[s];
    float e0 = as.x + ad.x; e0 = e0 >= 0.f ? e0 : 0.2f * e0;
    float e1 = as.y + ad.y; e1 = e1 >= 0.f ? e1 : 0.2f * e1;
    float e2 = as.z + ad.z; e2 = e2 >= 0.f ? e2 : 0.2f * e2;
    float e3 = as.w + ad.w; e3 = e3 >= 0.f ? e3 : 0.2f * e3;
    float p0 = __expf(e0), p1 = __expf(e1), p2 = __expf(e2), p3 = __expf(e3);
    float hv = __half2float(h1h[(size_t)s * 64 + lane]);
    l0 += p0; l1 += p1; l2 += p2; l3 += p3;
    ac0 += p0 * hv; ac1 += p1 * hv; ac2 += p2 * hv; ac3 += p3 * hv;
  }
  float* zr = z + (size_t)n * 256;
  zr[lane]       = ac0 / (4.f * (l0 + 1e-16f));
  zr[64 + lane]  = ac1 / (4.f * (l1 + 1e-16f));
  zr[128 + lane] = ac2 / (4.f * (l2 + 1e-16f));
  zr[192 + lane] = ac3 / (4.f * (l3 + 1e-16f));
}

// h2[n,d] = relu(bn2( z'[n,:] @ W2r[:,d] + b2[d] )). Weights in VGPRs (64/thread,
// wave w holds K-slice [w*64, w*64+64)), z rows staged in LDS, 64 nodes/block.
__global__ void __launch_bounds__(256) k_zproj(const float* __restrict__ z,
                      const float* __restrict__ W2r, const float* __restrict__ b2,
                      const float* __restrict__ g2, const float* __restrict__ bt2,
                      float* __restrict__ h2, __half* __restrict__ h2h){
  __shared__ float sz[4][256];
  __shared__ float sacc[4][4][64];
  int tid = threadIdx.x;
  int w = tid >> 6, d = tid & 63;
  float wreg[64];
  #pragma unroll
  for (int i = 0; i < 64; i++) wreg[i] = W2r[(w * 64 + i) * 64 + d];
  float gd = g2[d] * rsqrtf(1.f + 1e-5f), btd = bt2[d], bd = b2[d];
  int n0base = blockIdx.x * 64;
  for (int r = 0; r < 16; r++) {
    int n0 = n0base + r * 4;
    for (int i = tid; i < 1024; i += 256) {
      int m = i >> 8, c = i & 255;
      int n = n0 + m;
      sz[m][c] = (n < NN) ? z[(size_t)n * 256 + c] : 0.f;
    }
    __syncthreads();
    #pragma unroll
    for (int m = 0; m < 4; m++) {
      float acc = 0.f;
      #pragma unroll
      for (int i = 0; i < 64; i++) acc += sz[m][w * 64 + i] * wreg[i];
      sacc[m][w][d] = acc;
    }
    __syncthreads();
    int n = n0 + w;
    if (n < NN) {
      float rr = sacc[w][0][d] + sacc[w][1][d] + sacc[w][2][d] + sacc[w][3][d] + bd;
      rr = rr * gd + btd;
      rr = fmaxf(rr, 0.f);
      h2[(size_t)n * 64 + d] = rr;
      h2h[(size_t)n * 64 + d] = __float2half(rr);
    }
    __syncthreads();
  }
}

// agg3[n,d] = sum over incoming edges of h2h[src,d]; thread per (n, d)
__global__ void k_agg3_gather(const int* __restrict__ rowptr, const int* __restrict__ col,
                              const __half* __restrict__ h2h, float* __restrict__ agg3){
  int idx = blockIdx.x * 256 + threadIdx.x;
  int n = idx >> 6, d = idx & 63;
  if (n >= NN) return;
  int r0 = rowptr[n], r1 = rowptr[n + 1];
  float acc = 0.f;
  for (int j = r0; j < r1; j++) acc += __half2float(h2h[(size_t)col[j] * 64 + d]);
  agg3[idx] = acc;
}

// h3 = relu(bn3(agg3/deg @ Wl3 + h2 @ Wr3 + b3)) + (x @ Wskip + bskip); thread per (n,j), j<32
__global__ void k_sage3(const float* __restrict__ x, const float* __restrict__ h2,
                        const float* __restrict__ agg3, const int* __restrict__ count,
                        const float* __restrict__ Wl3, const float* __restrict__ Wr3,
                        const float* __restrict__ b3, const float* __restrict__ g3,
                        const float* __restrict__ bt3, const float* __restrict__ Wskip,
                        const float* __restrict__ bskip, float* __restrict__ h3){
  __shared__ float sWl[HID * CH], sWr[HID * CH], sWs[IN_F * CH];
  for (int i = threadIdx.x; i < HID * CH; i += 256) { sWl[i] = Wl3[i]; sWr[i] = Wr3[i]; }
  for (int i = threadIdx.x; i < IN_F * CH; i += 256) sWs[i] = Wskip[i];
  __syncthreads();
  int idx = blockIdx.x * 256 + threadIdx.x;
  if (idx >= NN * CH) return;
  int n = idx >> 5, j = idx & 31;
  float inv = 1.f / fmaxf((float)count[n], 1.f);
  float acc = b3[j];
  const float* ar = agg3 + n * HID;
  const float* hr = h2 + n * HID;
  #pragma unroll
  for (int k = 0; k < HID; k++)
    acc += (ar[k] * inv) * sWl[k * CH + j] + hr[k] * sWr[k * CH + j];
  acc = acc * (g3[j] * rsqrtf(1.f + 1e-5f)) + bt3[j];
  acc = fmaxf(acc, 0.f);
  float idn = bskip[j];
  const float* xr = x + n * IN_F;
  #pragma unroll
  for (int k = 0; k < IN_F; k++) idn += xr[k] * sWs[k * CH + j];
  h3[idx] = acc + idn;
}

// logits = relu(h3 @ Wc1 + bc1) @ Wc2 + bc2; log_softmax over 2 cols. Thread per node.
__global__ void k_cls(const float* __restrict__ h3, const float* __restrict__ Wc1,
                      const float* __restrict__ bc1, const float* __restrict__ Wc2,
                      const float* __restrict__ bc2, float* __restrict__ out){
  __shared__ float sW1[C1 * C1], sW2[C1 * OUTC], sb1[C1], sb2[OUTC];
  for (int i = threadIdx.x; i < C1 * C1; i += 256) sW1[i] = Wc1[i];
  if (threadIdx.x < C1 * OUTC) sW2[threadIdx.x] = Wc2[threadIdx.x];
  if (threadIdx.x < C1) sb1[threadIdx.x] = bc1[threadIdx.x];
  if (threadIdx.x < OUTC) sb2[threadIdx.x] = bc2[threadIdx.x];
  __syncthreads();
  int n = blockIdx.x * 256 + threadIdx.x;
  if (n >= NN) return;
  float hrow[CH];
  #pragma unroll
  for (int j = 0; j < CH; j++) hrow[j] = h3[n * CH + j];
  float l0 = sb2[0], l1 = sb2[1];
  #pragma unroll
  for (int i = 0; i < C1; i++) {
    float c = sb1[i];
    #pragma unroll
    for (int j = 0; j < CH; j++) c += hrow[j] * sW1[j * C1 + i];
    c = fmaxf(c, 0.f);
    l0 += c * sW2[i * OUTC + 0];
    l1 += c * sW2[i * OUTC + 1];
  }
  float mx = fmaxf(l0, l1);
  float lse = mx + logf(expf(l0 - mx) + expf(l1 - mx));
  out[n * OUTC + 0] = l0 - lse;
  out[n * OUTC + 1] = l1 - lse;
}

extern "C" void kernel_launch(void* const* d_in, const int* in_sizes, int n_in,
                              void* d_out, int out_size, void* d_ws, size_t ws_size,
                              hipStream_t stream) {
  const float* x       = (const float*)d_in[0];
  const int*   ei      = (const int*)d_in[1];
  const float* Wl1     = (const float*)d_in[2];
  const float* Wr1     = (const float*)d_in[3];
  const float* b1      = (const float*)d_in[4];
  const float* g1      = (const float*)d_in[5];
  const float* bt1     = (const float*)d_in[6];
  const float* W2      = (const float*)d_in[7];
  const float* att_src = (const float*)d_in[8];
  const float* att_dst = (const float*)d_in[9];
  const float* b2      = (const float*)d_in[10];
  const float* g2      = (const float*)d_in[11];
  const float* bt2     = (const float*)d_in[12];
  const float* Wl3     = (const float*)d_in[13];
  const float* Wr3     = (const float*)d_in[14];
  const float* b3      = (const float*)d_in[15];
  const float* g3      = (const float*)d_in[16];
  const float* bt3     = (const float*)d_in[17];
  const float* Wskip   = (const float*)d_in[18];
  const float* bskip   = (const float*)d_in[19];
  const float* Wc1     = (const float*)d_in[20];
  const float* bc1     = (const float*)d_in[21];
  const float* Wc2     = (const float*)d_in[22];
  const float* bc2     = (const float*)d_in[23];
  float* out = (float*)d_out;

  const int* src = ei;
  const int* dst = ei + NE;

  float* ws = (float*)d_ws;
  size_t off = 0;
  auto alloc = [&](size_t nf) { size_t o = off; off += (nf + 63) & ~(size_t)63; return o; };
  // zero region (ints): count, cnt2 — contiguous
  size_t o_count = alloc(NN);
  size_t o_cnt2  = alloc(NN);
  size_t zero_elems = off;
  size_t o_rowptr = alloc(NN + 1);
  size_t o_bsum   = alloc(256);
  size_t o_bsumex = alloc(256);
  size_t o_col    = alloc(NE);
  size_t o_xh     = alloc((size_t)NN * IN_F / 2 + 64);      // fp16
  size_t o_aggx   = alloc((size_t)NN * IN_F);
  size_t o_h1h    = alloc((size_t)NN * HID / 2 + 64);       // fp16
  size_t o_as     = alloc((size_t)NN * HEADS);
  size_t o_ad     = alloc((size_t)NN * HEADS);
  size_t o_was    = alloc(256);
  size_t o_wad    = alloc(256);
  size_t o_w2r    = alloc(256 * 64);
  size_t o_z      = alloc((size_t)NN * 256);
  size_t o_h2     = alloc((size_t)NN * HID);
  size_t o_h2h    = alloc((size_t)NN * HID / 2 + 64);       // fp16
  size_t o_agg3   = alloc((size_t)NN * HID);
  size_t o_h3     = alloc((size_t)NN * CH);
  (void)ws_size; (void)in_sizes; (void)n_in; (void)out_size;

  int* count    = (int*)(ws + o_count);
  int* cnt2     = (int*)(ws + o_cnt2);
  int* rowptr   = (int*)(ws + o_rowptr);
  int* bsum     = (int*)(ws + o_bsum);
  int* bsumex   = (int*)(ws + o_bsumex);
  int* col      = (int*)(ws + o_col);
  __half* xh    = (__half*)(ws + o_xh);
  float* aggx   = ws + o_aggx;
  __half* h1h   = (__half*)(ws + o_h1h);
  float* a_s    = ws + o_as;
  float* a_d    = ws + o_ad;
  float* was    = ws + o_was;
  float* wad    = ws + o_wad;
  float* W2r    = ws + o_w2r;
  float* z      = ws + o_z;
  float* h2     = ws + o_h2;
  __half* h2h   = (__half*)(ws + o_h2h);
  float* agg3   = ws + o_agg3;
  float* h3     = ws + o_h3;

  auto nb = [](long long n) { return (int)((n + 255) / 256); };
  const int nscan = nb(NN);  // 196

  k_zero_i<<<nb((long long)zero_elems), 256, 0, stream>>>((int*)ws, (int)zero_elems);
  k_count<<<nb(NE), 256, 0, stream>>>(dst, count);
  k_scan_block<<<nscan, 256, 0, stream>>>(count, rowptr, bsum, NN);
  k_scan_block<<<1, 256, 0, stream>>>(bsum, bsumex, nullptr, nscan);
  k_add_off<<<nscan, 256, 0, stream>>>(rowptr, bsumex, NN);
  k_scatter<<<nb(NE), 256, 0, stream>>>(src, dst, rowptr, cnt2, col);
  k_xhalf<<<nb((long long)NN * IN_F), 256, 0, stream>>>(x, xh);
  k_was<<<1, 256, 0, stream>>>(W2, att_src, att_dst, was, wad);
  k_w2r<<<64, 256, 0, stream>>>(W2, W2r);
  k_aggx_gather<<<nb((long long)NN * 32), 256, 0, stream>>>(rowptr, col, xh, aggx);
  k_sage1<<<nb((long long)NN * HID), 256, 0, stream>>>(x, aggx, count, Wl1, Wr1, b1, g1, bt1,
                                                       was, wad, h1h, a_s, a_d);
  k_gat_fused<<<nb((long long)NN * 64), 256, 0, stream>>>(rowptr, col, (const float4*)a_s,
                                                          (const float4*)a_d, h1h, z);
  k_zproj<<<(NN + 63) / 64, 256, 0, stream>>>(z, W2r, b2, g2, bt2, h2, h2h);
  k_agg3_gather<<<nb((long long)NN * 64), 256, 0, stream>>>(rowptr, col, h2h, agg3);
  k_sage3<<<nb((long long)NN * CH), 256, 0, stream>>>(x, h2, agg3, count, Wl3, Wr3, b3, g3, bt3,
                                                      Wskip, bskip, h3);
  k_cls<<<nb(NN), 256, 0, stream>>>(h3, Wc1, bc1, Wc2, bc2, out);
}

// Round 4
// 352.449 us; speedup vs baseline: 5.8933x; 1.2660x over previous
//
#include <hip/hip_runtime.h>
#include <hip/hip_fp16.h>
#include <math.h>

#define NN 50000
#define NE 800000
#define IN_F 20
#define HID 64
#define HEADS 4
#define HD 64
#define CH 32      // hidden//2
#define C1 32      // classifier hidden
#define OUTC 2

__global__ void k_zero_i(int* __restrict__ p, int n){
  int i = blockIdx.x * 256 + threadIdx.x;
  if (i < n) p[i] = 0;
}

// count[d] = in-degree
__global__ void k_count(const int* __restrict__ dst, int* __restrict__ count){
  int e = blockIdx.x * 256 + threadIdx.x;
  if (e < NE) atomicAdd(&count[dst[e]], 1);
}

// per-block exclusive scan (256 elems); block sums out
__global__ void k_scan_block(const int* __restrict__ in, int* __restrict__ out,
                             int* __restrict__ bsum, int n){
  __shared__ int tmp[256];
  int g = blockIdx.x * 256 + threadIdx.x;
  int v = (g < n) ? in[g] : 0;
  tmp[threadIdx.x] = v;
  __syncthreads();
  for (int o = 1; o < 256; o <<= 1) {
    int t = ((int)threadIdx.x >= o) ? tmp[threadIdx.x - o] : 0;
    __syncthreads();
    tmp[threadIdx.x] += t;
    __syncthreads();
  }
  if (g < n) out[g] = tmp[threadIdx.x] - v;   // exclusive
  if (bsum && threadIdx.x == 255) bsum[blockIdx.x] = tmp[255];
}

__global__ void k_add_off(int* __restrict__ rowptr, const int* __restrict__ bsum_ex, int n){
  int g = blockIdx.x * 256 + threadIdx.x;
  if (g < n) rowptr[g] += bsum_ex[g >> 8];
  if (g == 0) rowptr[NN] = NE;
}

// col[rowptr[d] + slot] = src[e]; rowid[slot] = d
__global__ void k_scatter(const int* __restrict__ src, const int* __restrict__ dst,
                          const int* __restrict__ rowptr, int* __restrict__ cnt2,
                          int* __restrict__ col, int* __restrict__ rowid){
  int e = blockIdx.x * 256 + threadIdx.x;
  if (e >= NE) return;
  int d = dst[e];
  int p = rowptr[d] + atomicAdd(&cnt2[d], 1);
  col[p] = src[e];
  rowid[p] = d;
}

// x -> fp16 copy
__global__ void k_xhalf(const float* __restrict__ x, __half* __restrict__ xh){
  int i = blockIdx.x * 256 + threadIdx.x;
  if (i < NN * IN_F) xh[i] = __float2half(x[i]);
}

// was[h][k] = sum_d W2[k, h*64+d]*att_src[h][d]; wad likewise. One block of 256.
__global__ void k_was(const float* __restrict__ W2, const float* __restrict__ att_src,
                      const float* __restrict__ att_dst,
                      float* __restrict__ was, float* __restrict__ wad){
  int t = threadIdx.x;          // t = h*64 + k
  int h = t >> 6, k = t & 63;
  float s = 0.f, dd = 0.f;
  for (int d = 0; d < 64; d++) {
    float w = W2[k * 256 + h * 64 + d];
    s  += w * att_src[h * 64 + d];
    dd += w * att_dst[h * 64 + d];
  }
  was[t] = s; wad[t] = dd;
}

// W2r[(h*64+k)*64 + d] = W2[k*256 + h*64 + d]
__global__ void k_w2r(const float* __restrict__ W2, float* __restrict__ W2r){
  int i = blockIdx.x * 256 + threadIdx.x;
  if (i >= 256 * 64) return;
  int hk = i >> 6, d = i & 63;
  int h = hk >> 6, k = hk & 63;
  W2r[i] = W2[k * 256 + h * 64 + d];
}

// aggx[n,k] = sum over incoming edges of xh[src,k]; thread per (n, k) with k padded to 32
__global__ void k_aggx_gather(const int* __restrict__ rowptr, const int* __restrict__ col,
                              const __half* __restrict__ xh, float* __restrict__ aggx){
  int idx = blockIdx.x * 256 + threadIdx.x;
  int n = idx >> 5, k = idx & 31;
  if (n >= NN || k >= IN_F) return;
  int r0 = rowptr[n], r1 = rowptr[n + 1];
  float acc = 0.f;
  int j = r0;
  for (; j + 4 <= r1; j += 4) {
    int s0 = col[j], s1 = col[j+1], s2 = col[j+2], s3 = col[j+3];
    float v0 = __half2float(xh[s0 * IN_F + k]);
    float v1 = __half2float(xh[s1 * IN_F + k]);
    float v2 = __half2float(xh[s2 * IN_F + k]);
    float v3 = __half2float(xh[s3 * IN_F + k]);
    acc += (v0 + v1) + (v2 + v3);
  }
  for (; j < r1; j++) acc += __half2float(xh[col[j] * IN_F + k]);
  aggx[n * IN_F + k] = acc;
}

// h1 = relu(bn1(aggx/deg @ Wl1 + x @ Wr1 + b1)); writes fp16 h1h + attention logits
__global__ void k_sage1(const float* __restrict__ x, const float* __restrict__ aggx,
                        const int* __restrict__ count,
                        const float* __restrict__ Wl, const float* __restrict__ Wr,
                        const float* __restrict__ b, const float* __restrict__ g,
                        const float* __restrict__ bt,
                        const float* __restrict__ was, const float* __restrict__ wad,
                        __half* __restrict__ h1h, float* __restrict__ a_s,
                        float* __restrict__ a_d){
  __shared__ float sWl[IN_F * HID], sWr[IN_F * HID], sWas[256], sWad[256];
  for (int i = threadIdx.x; i < IN_F * HID; i += 256) { sWl[i] = Wl[i]; sWr[i] = Wr[i]; }
  { int i = threadIdx.x; sWas[i] = was[i]; sWad[i] = wad[i]; }
  __syncthreads();
  int idx = blockIdx.x * 256 + threadIdx.x;
  if (idx >= NN * HID) return;
  int n = idx >> 6, j = idx & 63;
  float inv = 1.f / fmaxf((float)count[n], 1.f);
  const float* xr = x + n * IN_F;
  const float* ar = aggx + n * IN_F;
  float acc = b[j];
  #pragma unroll
  for (int k = 0; k < IN_F; k++)
    acc += (ar[k] * inv) * sWl[k * HID + j] + xr[k] * sWr[k * HID + j];
  acc = acc * (g[j] * rsqrtf(1.f + 1e-5f)) + bt[j];
  acc = fmaxf(acc, 0.f);
  h1h[idx] = __float2half(acc);
  #pragma unroll
  for (int h = 0; h < HEADS; h++) {
    float vs = acc * sWas[h * 64 + j];
    float vd = acc * sWad[h * 64 + j];
    #pragma unroll
    for (int o = 32; o > 0; o >>= 1) { vs += __shfl_down(vs, o); vd += __shfl_down(vd, o); }
    if (j == 0) { a_s[n * 4 + h] = vs; a_d[n * 4 + h] = vd; }
  }
}

// edge-parallel: pe[j] = exp(leaky(a_s[col[j]] + a_d[rowid[j]])) per head (CSR slot order)
__global__ void k_edgep(const int* __restrict__ col, const int* __restrict__ rowid,
                        const float4* __restrict__ a_s4, const float4* __restrict__ a_d4,
                        float4* __restrict__ pe4){
  int j = blockIdx.x * 256 + threadIdx.x;
  if (j >= NE) return;
  float4 as = a_s4[col[j]];
  float4 ad = a_d4[rowid[j]];
  float e0 = as.x + ad.x; e0 = e0 >= 0.f ? e0 : 0.2f * e0;
  float e1 = as.y + ad.y; e1 = e1 >= 0.f ? e1 : 0.2f * e1;
  float e2 = as.z + ad.z; e2 = e2 >= 0.f ? e2 : 0.2f * e2;
  float e3 = as.w + ad.w; e3 = e3 >= 0.f ? e3 : 0.2f * e3;
  pe4[j] = make_float4(__expf(e0), __expf(e1), __expf(e2), __expf(e3));
}

// Fused GAT: per node (one wave, lane = h1 feature k), single pass over edges.
// z'[n, h*64+k] = (sum_e pe_h * h1[src][k]) / (4*(sum_e pe_h + 1e-16)), stored fp16
__global__ void k_gat_fused(const int* __restrict__ rowptr, const int* __restrict__ col,
                            const float4* __restrict__ pe4,
                            const __half* __restrict__ h1h, __half* __restrict__ z){
  int wid = threadIdx.x >> 6;
  int lane = threadIdx.x & 63;
  int n = blockIdx.x * 4 + wid;
  if (n >= NN) return;
  int r0 = rowptr[n], r1 = rowptr[n + 1];
  float l0 = 0.f, l1 = 0.f, l2 = 0.f, l3 = 0.f;
  float ac0 = 0.f, ac1 = 0.f, ac2 = 0.f, ac3 = 0.f;
  int j = r0;
  for (; j + 4 <= r1; j += 4) {
    int s0 = col[j], s1 = col[j+1], s2 = col[j+2], s3 = col[j+3];
    float4 p0 = pe4[j], p1 = pe4[j+1], p2 = pe4[j+2], p3 = pe4[j+3];
    float v0 = __half2float(h1h[(size_t)s0 * 64 + lane]);
    float v1 = __half2float(h1h[(size_t)s1 * 64 + lane]);
    float v2 = __half2float(h1h[(size_t)s2 * 64 + lane]);
    float v3 = __half2float(h1h[(size_t)s3 * 64 + lane]);
    l0 += (p0.x + p1.x) + (p2.x + p3.x);
    l1 += (p0.y + p1.y) + (p2.y + p3.y);
    l2 += (p0.z + p1.z) + (p2.z + p3.z);
    l3 += (p0.w + p1.w) + (p2.w + p3.w);
    ac0 += p0.x * v0 + p1.x * v1 + p2.x * v2 + p3.x * v3;
    ac1 += p0.y * v0 + p1.y * v1 + p2.y * v2 + p3.y * v3;
    ac2 += p0.z * v0 + p1.z * v1 + p2.z * v2 + p3.z * v3;
    ac3 += p0.w * v0 + p1.w * v1 + p2.w * v2 + p3.w * v3;
  }
  for (; j < r1; j++) {
    int s = col[j];
    float4 p = pe4[j];
    float v = __half2float(h1h[(size_t)s * 64 + lane]);
    l0 += p.x; l1 += p.y; l2 += p.z; l3 += p.w;
    ac0 += p.x * v; ac1 += p.y * v; ac2 += p.z * v; ac3 += p.w * v;
  }
  __half* zr = z + (size_t)n * 256;
  zr[lane]       = __float2half(ac0 / (4.f * (l0 + 1e-16f)));
  zr[64 + lane]  = __float2half(ac1 / (4.f * (l1 + 1e-16f)));
  zr[128 + lane] = __float2half(ac2 / (4.f * (l2 + 1e-16f)));
  zr[192 + lane] = __float2half(ac3 / (4.f * (l3 + 1e-16f)));
}

// h2[n,d] = relu(bn2( z'[n,:] @ W2r[:,d] + b2[d] )). Weights in VGPRs (64/thread,
// wave w holds K-slice [w*64, w*64+64)), z rows staged in LDS, 64 nodes/block.
__global__ void __launch_bounds__(256) k_zproj(const __half* __restrict__ z,
                      const float* __restrict__ W2r, const float* __restrict__ b2,
                      const float* __restrict__ g2, const float* __restrict__ bt2,
                      float* __restrict__ h2, __half* __restrict__ h2h){
  __shared__ float sz[4][256];
  __shared__ float sacc[4][4][64];
  int tid = threadIdx.x;
  int w = tid >> 6, d = tid & 63;
  float wreg[64];
  #pragma unroll
  for (int i = 0; i < 64; i++) wreg[i] = W2r[(w * 64 + i) * 64 + d];
  float gd = g2[d] * rsqrtf(1.f + 1e-5f), btd = bt2[d], bd = b2[d];
  int n0base = blockIdx.x * 64;
  for (int r = 0; r < 16; r++) {
    int n0 = n0base + r * 4;
    for (int i = tid; i < 512; i += 256) {
      int m = i >> 7, c = (i & 127) * 2;
      int n = n0 + m;
      if (n < NN) {
        __half2 hv = *(const __half2*)(z + (size_t)n * 256 + c);
        float2 f = __half22float2(hv);
        sz[m][c] = f.x; sz[m][c + 1] = f.y;
      } else { sz[m][c] = 0.f; sz[m][c + 1] = 0.f; }
    }
    __syncthreads();
    #pragma unroll
    for (int m = 0; m < 4; m++) {
      float acc = 0.f;
      #pragma unroll
      for (int i = 0; i < 64; i++) acc += sz[m][w * 64 + i] * wreg[i];
      sacc[m][w][d] = acc;
    }
    __syncthreads();
    int n = n0 + w;
    if (n < NN) {
      float rr = sacc[w][0][d] + sacc[w][1][d] + sacc[w][2][d] + sacc[w][3][d] + bd;
      rr = rr * gd + btd;
      rr = fmaxf(rr, 0.f);
      h2[(size_t)n * 64 + d] = rr;
      h2h[(size_t)n * 64 + d] = __float2half(rr);
    }
    __syncthreads();
  }
}

// agg3[n,d] = sum over incoming edges of h2h[src,d]; wave per node, lane = d, unroll 4
__global__ void k_agg3_gather(const int* __restrict__ rowptr, const int* __restrict__ col,
                              const __half* __restrict__ h2h, float* __restrict__ agg3){
  int idx = blockIdx.x * 256 + threadIdx.x;
  int n = idx >> 6, d = idx & 63;
  if (n >= NN) return;
  int r0 = rowptr[n], r1 = rowptr[n + 1];
  float acc = 0.f;
  int j = r0;
  for (; j + 4 <= r1; j += 4) {
    int s0 = col[j], s1 = col[j+1], s2 = col[j+2], s3 = col[j+3];
    float v0 = __half2float(h2h[(size_t)s0 * 64 + d]);
    float v1 = __half2float(h2h[(size_t)s1 * 64 + d]);
    float v2 = __half2float(h2h[(size_t)s2 * 64 + d]);
    float v3 = __half2float(h2h[(size_t)s3 * 64 + d]);
    acc += (v0 + v1) + (v2 + v3);
  }
  for (; j < r1; j++) acc += __half2float(h2h[(size_t)col[j] * 64 + d]);
  agg3[idx] = acc;
}

// h3 = relu(bn3(agg3/deg @ Wl3 + h2 @ Wr3 + b3)) + (x @ Wskip + bskip); thread per (n,j), j<32
__global__ void k_sage3(const float* __restrict__ x, const float* __restrict__ h2,
                        const float* __restrict__ agg3, const int* __restrict__ count,
                        const float* __restrict__ Wl3, const float* __restrict__ Wr3,
                        const float* __restrict__ b3, const float* __restrict__ g3,
                        const float* __restrict__ bt3, const float* __restrict__ Wskip,
                        const float* __restrict__ bskip, float* __restrict__ h3){
  __shared__ float sWl[HID * CH], sWr[HID * CH], sWs[IN_F * CH];
  for (int i = threadIdx.x; i < HID * CH; i += 256) { sWl[i] = Wl3[i]; sWr[i] = Wr3[i]; }
  for (int i = threadIdx.x; i < IN_F * CH; i += 256) sWs[i] = Wskip[i];
  __syncthreads();
  int idx = blockIdx.x * 256 + threadIdx.x;
  if (idx >= NN * CH) return;
  int n = idx >> 5, j = idx & 31;
  float inv = 1.f / fmaxf((float)count[n], 1.f);
  float acc = b3[j];
  const float* ar = agg3 + n * HID;
  const float* hr = h2 + n * HID;
  #pragma unroll
  for (int k = 0; k < HID; k++)
    acc += (ar[k] * inv) * sWl[k * CH + j] + hr[k] * sWr[k * CH + j];
  acc = acc * (g3[j] * rsqrtf(1.f + 1e-5f)) + bt3[j];
  acc = fmaxf(acc, 0.f);
  float idn = bskip[j];
  const float* xr = x + n * IN_F;
  #pragma unroll
  for (int k = 0; k < IN_F; k++) idn += xr[k] * sWs[k * CH + j];
  h3[idx] = acc + idn;
}

// logits = relu(h3 @ Wc1 + bc1) @ Wc2 + bc2; log_softmax over 2 cols. Thread per node.
__global__ void k_cls(const float* __restrict__ h3, const float* __restrict__ Wc1,
                      const float* __restrict__ bc1, const float* __restrict__ Wc2,
                      const float* __restrict__ bc2, float* __restrict__ out){
  __shared__ float sW1[C1 * C1], sW2[C1 * OUTC], sb1[C1], sb2[OUTC];
  for (int i = threadIdx.x; i < C1 * C1; i += 256) sW1[i] = Wc1[i];
  if (threadIdx.x < C1 * OUTC) sW2[threadIdx.x] = Wc2[threadIdx.x];
  if (threadIdx.x < C1) sb1[threadIdx.x] = bc1[threadIdx.x];
  if (threadIdx.x < OUTC) sb2[threadIdx.x] = bc2[threadIdx.x];
  __syncthreads();
  int n = blockIdx.x * 256 + threadIdx.x;
  if (n >= NN) return;
  float hrow[CH];
  #pragma unroll
  for (int j = 0; j < CH; j++) hrow[j] = h3[n * CH + j];
  float l0 = sb2[0], l1 = sb2[1];
  #pragma unroll
  for (int i = 0; i < C1; i++) {
    float c = sb1[i];
    #pragma unroll
    for (int j = 0; j < CH; j++) c += hrow[j] * sW1[j * C1 + i];
    c = fmaxf(c, 0.f);
    l0 += c * sW2[i * OUTC + 0];
    l1 += c * sW2[i * OUTC + 1];
  }
  float mx = fmaxf(l0, l1);
  float lse = mx + logf(expf(l0 - mx) + expf(l1 - mx));
  out[n * OUTC + 0] = l0 - lse;
  out[n * OUTC + 1] = l1 - lse;
}

extern "C" void kernel_launch(void* const* d_in, const int* in_sizes, int n_in,
                              void* d_out, int out_size, void* d_ws, size_t ws_size,
                              hipStream_t stream) {
  const float* x       = (const float*)d_in[0];
  const int*   ei      = (const int*)d_in[1];
  const float* Wl1     = (const float*)d_in[2];
  const float* Wr1     = (const float*)d_in[3];
  const float* b1      = (const float*)d_in[4];
  const float* g1      = (const float*)d_in[5];
  const float* bt1     = (const float*)d_in[6];
  const float* W2      = (const float*)d_in[7];
  const float* att_src = (const float*)d_in[8];
  const float* att_dst = (const float*)d_in[9];
  const float* b2      = (const float*)d_in[10];
  const float* g2      = (const float*)d_in[11];
  const float* bt2     = (const float*)d_in[12];
  const float* Wl3     = (const float*)d_in[13];
  const float* Wr3     = (const float*)d_in[14];
  const float* b3      = (const float*)d_in[15];
  const float* g3      = (const float*)d_in[16];
  const float* bt3     = (const float*)d_in[17];
  const float* Wskip   = (const float*)d_in[18];
  const float* bskip   = (const float*)d_in[19];
  const float* Wc1     = (const float*)d_in[20];
  const float* bc1     = (const float*)d_in[21];
  const float* Wc2     = (const float*)d_in[22];
  const float* bc2     = (const float*)d_in[23];
  float* out = (float*)d_out;

  const int* src = ei;
  const int* dst = ei + NE;

  float* ws = (float*)d_ws;
  size_t off = 0;
  auto alloc = [&](size_t nf) { size_t o = off; off += (nf + 63) & ~(size_t)63; return o; };
  // zero region (ints): count, cnt2 — contiguous
  size_t o_count = alloc(NN);
  size_t o_cnt2  = alloc(NN);
  size_t zero_elems = off;
  size_t o_rowptr = alloc(NN + 1);
  size_t o_bsum   = alloc(256);
  size_t o_bsumex = alloc(256);
  size_t o_col    = alloc(NE);
  size_t o_rowid  = alloc(NE);
  size_t o_pe     = alloc((size_t)NE * 4);
  size_t o_xh     = alloc((size_t)NN * IN_F / 2 + 64);      // fp16
  size_t o_aggx   = alloc((size_t)NN * IN_F);
  size_t o_h1h    = alloc((size_t)NN * HID / 2 + 64);       // fp16
  size_t o_as     = alloc((size_t)NN * HEADS);
  size_t o_ad     = alloc((size_t)NN * HEADS);
  size_t o_was    = alloc(256);
  size_t o_wad    = alloc(256);
  size_t o_w2r    = alloc(256 * 64);
  size_t o_z      = alloc((size_t)NN * 256 / 2 + 64);       // fp16
  size_t o_h2     = alloc((size_t)NN * HID);
  size_t o_h2h    = alloc((size_t)NN * HID / 2 + 64);       // fp16
  size_t o_agg3   = alloc((size_t)NN * HID);
  size_t o_h3     = alloc((size_t)NN * CH);
  (void)ws_size; (void)in_sizes; (void)n_in; (void)out_size;

  int* count    = (int*)(ws + o_count);
  int* cnt2     = (int*)(ws + o_cnt2);
  int* rowptr   = (int*)(ws + o_rowptr);
  int* bsum     = (int*)(ws + o_bsum);
  int* bsumex   = (int*)(ws + o_bsumex);
  int* col      = (int*)(ws + o_col);
  int* rowid    = (int*)(ws + o_rowid);
  float* pe     = ws + o_pe;
  __half* xh    = (__half*)(ws + o_xh);
  float* aggx   = ws + o_aggx;
  __half* h1h   = (__half*)(ws + o_h1h);
  float* a_s    = ws + o_as;
  float* a_d    = ws + o_ad;
  float* was    = ws + o_was;
  float* wad    = ws + o_wad;
  float* W2r    = ws + o_w2r;
  __half* z     = (__half*)(ws + o_z);
  float* h2     = ws + o_h2;
  __half* h2h   = (__half*)(ws + o_h2h);
  float* agg3   = ws + o_agg3;
  float* h3     = ws + o_h3;

  auto nb = [](long long n) { return (int)((n + 255) / 256); };
  const int nscan = nb(NN);  // 196

  k_zero_i<<<nb((long long)zero_elems), 256, 0, stream>>>((int*)ws, (int)zero_elems);
  k_count<<<nb(NE), 256, 0, stream>>>(dst, count);
  k_scan_block<<<nscan, 256, 0, stream>>>(count, rowptr, bsum, NN);
  k_scan_block<<<1, 256, 0, stream>>>(bsum, bsumex, nullptr, nscan);
  k_add_off<<<nscan, 256, 0, stream>>>(rowptr, bsumex, NN);
  k_scatter<<<nb(NE), 256, 0, stream>>>(src, dst, rowptr, cnt2, col, rowid);
  k_xhalf<<<nb((long long)NN * IN_F), 256, 0, stream>>>(x, xh);
  k_was<<<1, 256, 0, stream>>>(W2, att_src, att_dst, was, wad);
  k_w2r<<<64, 256, 0, stream>>>(W2, W2r);
  k_aggx_gather<<<nb((long long)NN * 32), 256, 0, stream>>>(rowptr, col, xh, aggx);
  k_sage1<<<nb((long long)NN * HID), 256, 0, stream>>>(x, aggx, count, Wl1, Wr1, b1, g1, bt1,
                                                       was, wad, h1h, a_s, a_d);
  k_edgep<<<nb(NE), 256, 0, stream>>>(col, rowid, (const float4*)a_s, (const float4*)a_d,
                                      (float4*)pe);
  k_gat_fused<<<nb((long long)NN * 64), 256, 0, stream>>>(rowptr, col, (const float4*)pe, h1h, z);
  k_zproj<<<(NN + 63) / 64, 256, 0, stream>>>(z, W2r, b2, g2, bt2, h2, h2h);
  k_agg3_gather<<<nb((long long)NN * 64), 256, 0, stream>>>(rowptr, col, h2h, agg3);
  k_sage3<<<nb((long long)NN * CH), 256, 0, stream>>>(x, h2, agg3, count, Wl3, Wr3, b3, g3, bt3,
                                                      Wskip, bskip, h3);
  k_cls<<<nb(NN), 256, 0, stream>>>(h3, Wc1, bc1, Wc2, bc2, out);
}

// Round 5
// 342.910 us; speedup vs baseline: 6.0572x; 1.0278x over previous
//
#include <hip/hip_runtime.h>
#include <hip/hip_fp16.h>
#include <math.h>

#define NN 50000
#define NE 800000
#define IN_F 20
#define HID 64
#define HEADS 4
#define HD 64
#define CH 32      // hidden//2
#define C1 32      // classifier hidden
#define OUTC 2

// count[d] = in-degree
__global__ void k_count(const int* __restrict__ dst, int* __restrict__ count){
  int e = blockIdx.x * 256 + threadIdx.x;
  if (e < NE) atomicAdd(&count[dst[e]], 1);
}

// per-block exclusive scan (256 elems); block sums out
__global__ void k_scan_block(const int* __restrict__ in, int* __restrict__ out,
                             int* __restrict__ bsum, int n){
  __shared__ int tmp[256];
  int g = blockIdx.x * 256 + threadIdx.x;
  int v = (g < n) ? in[g] : 0;
  tmp[threadIdx.x] = v;
  __syncthreads();
  for (int o = 1; o < 256; o <<= 1) {
    int t = ((int)threadIdx.x >= o) ? tmp[threadIdx.x - o] : 0;
    __syncthreads();
    tmp[threadIdx.x] += t;
    __syncthreads();
  }
  if (g < n) out[g] = tmp[threadIdx.x] - v;   // exclusive
  if (bsum && threadIdx.x == 255) bsum[blockIdx.x] = tmp[255];
}

__global__ void k_add_off(int* __restrict__ rowptr, const int* __restrict__ bsum_ex, int n){
  int g = blockIdx.x * 256 + threadIdx.x;
  if (g < n) rowptr[g] += bsum_ex[g >> 8];
  if (g == 0) rowptr[NN] = NE;
}

// colrow[rowptr[d] + slot] = (src[e], d)  — single 8B scattered store per edge
__global__ void k_scatter(const int* __restrict__ src, const int* __restrict__ dst,
                          const int* __restrict__ rowptr, int* __restrict__ cnt2,
                          int2* __restrict__ colrow){
  int e = blockIdx.x * 256 + threadIdx.x;
  if (e >= NE) return;
  int d = dst[e];
  int p = rowptr[d] + atomicAdd(&cnt2[d], 1);
  colrow[p] = make_int2(src[e], d);
}

// fused prep: xh = fp16(x); was/wad folded attention vectors; W2r reordered
__global__ void k_prep(const float* __restrict__ x, const float* __restrict__ W2,
                       const float* __restrict__ att_src, const float* __restrict__ att_dst,
                       __half* __restrict__ xh, float* __restrict__ was,
                       float* __restrict__ wad, float* __restrict__ W2r){
  int i = blockIdx.x * 256 + threadIdx.x;
  if (i < NN * IN_F) xh[i] = __float2half(x[i]);
  if (i < 256 * 64) {
    int hk = i >> 6, d = i & 63;
    int h = hk >> 6, k = hk & 63;
    W2r[i] = W2[k * 256 + h * 64 + d];
  }
  if (i < 256) {
    int h = i >> 6, k = i & 63;
    float s = 0.f, dd = 0.f;
    for (int d = 0; d < 64; d++) {
      float w = W2[k * 256 + h * 64 + d];
      s  += w * att_src[h * 64 + d];
      dd += w * att_dst[h * 64 + d];
    }
    was[i] = s; wad[i] = dd;
  }
}

// aggx[n,k] = sum over incoming edges of xh[src,k]; exact thread per (n, k<20)
__global__ void k_aggx_gather(const int* __restrict__ rowptr, const int2* __restrict__ colrow,
                              const __half* __restrict__ xh, float* __restrict__ aggx){
  int idx = blockIdx.x * 256 + threadIdx.x;
  if (idx >= NN * IN_F) return;
  int n = idx / IN_F, k = idx - n * IN_F;
  int r0 = rowptr[n], r1 = rowptr[n + 1];
  float acc = 0.f;
  int j = r0;
  for (; j + 4 <= r1; j += 4) {
    int s0 = colrow[j].x, s1 = colrow[j+1].x, s2 = colrow[j+2].x, s3 = colrow[j+3].x;
    float v0 = __half2float(xh[s0 * IN_F + k]);
    float v1 = __half2float(xh[s1 * IN_F + k]);
    float v2 = __half2float(xh[s2 * IN_F + k]);
    float v3 = __half2float(xh[s3 * IN_F + k]);
    acc += (v0 + v1) + (v2 + v3);
  }
  for (; j < r1; j++) acc += __half2float(xh[colrow[j].x * IN_F + k]);
  aggx[idx] = acc;
}

// h1 = relu(bn1(aggx/deg @ Wl1 + x @ Wr1 + b1)); writes fp16 h1h + attention logits
__global__ void k_sage1(const float* __restrict__ x, const float* __restrict__ aggx,
                        const int* __restrict__ count,
                        const float* __restrict__ Wl, const float* __restrict__ Wr,
                        const float* __restrict__ b, const float* __restrict__ g,
                        const float* __restrict__ bt,
                        const float* __restrict__ was, const float* __restrict__ wad,
                        __half* __restrict__ h1h, float* __restrict__ a_s,
                        float* __restrict__ a_d){
  __shared__ float sWl[IN_F * HID], sWr[IN_F * HID], sWas[256], sWad[256];
  for (int i = threadIdx.x; i < IN_F * HID; i += 256) { sWl[i] = Wl[i]; sWr[i] = Wr[i]; }
  { int i = threadIdx.x; sWas[i] = was[i]; sWad[i] = wad[i]; }
  __syncthreads();
  int idx = blockIdx.x * 256 + threadIdx.x;
  if (idx >= NN * HID) return;
  int n = idx >> 6, j = idx & 63;
  float inv = 1.f / fmaxf((float)count[n], 1.f);
  const float* xr = x + n * IN_F;
  const float* ar = aggx + n * IN_F;
  float acc = b[j];
  #pragma unroll
  for (int k = 0; k < IN_F; k++)
    acc += (ar[k] * inv) * sWl[k * HID + j] + xr[k] * sWr[k * HID + j];
  acc = acc * (g[j] * rsqrtf(1.f + 1e-5f)) + bt[j];
  acc = fmaxf(acc, 0.f);
  h1h[idx] = __float2half(acc);
  #pragma unroll
  for (int h = 0; h < HEADS; h++) {
    float vs = acc * sWas[h * 64 + j];
    float vd = acc * sWad[h * 64 + j];
    #pragma unroll
    for (int o = 32; o > 0; o >>= 1) { vs += __shfl_down(vs, o); vd += __shfl_down(vd, o); }
    if (j == 0) { a_s[n * 4 + h] = vs; a_d[n * 4 + h] = vd; }
  }
}

// edge-parallel: pe[j] = exp(leaky(a_s[col[j]] + a_d[row[j]])) per head (CSR slot order)
__global__ void k_edgep(const int2* __restrict__ colrow,
                        const float4* __restrict__ a_s4, const float4* __restrict__ a_d4,
                        float4* __restrict__ pe4){
  int j = blockIdx.x * 256 + threadIdx.x;
  if (j >= NE) return;
  int2 cr = colrow[j];
  float4 as = a_s4[cr.x];
  float4 ad = a_d4[cr.y];
  float e0 = as.x + ad.x; e0 = e0 >= 0.f ? e0 : 0.2f * e0;
  float e1 = as.y + ad.y; e1 = e1 >= 0.f ? e1 : 0.2f * e1;
  float e2 = as.z + ad.z; e2 = e2 >= 0.f ? e2 : 0.2f * e2;
  float e3 = as.w + ad.w; e3 = e3 >= 0.f ? e3 : 0.2f * e3;
  pe4[j] = make_float4(__expf(e0), __expf(e1), __expf(e2), __expf(e3));
}

// Fused GAT: per node (one wave, lane = h1 feature k), single pass over edges.
__global__ void k_gat_fused(const int* __restrict__ rowptr, const int2* __restrict__ colrow,
                            const float4* __restrict__ pe4,
                            const __half* __restrict__ h1h, __half* __restrict__ z){
  int wid = threadIdx.x >> 6;
  int lane = threadIdx.x & 63;
  int n = blockIdx.x * 4 + wid;
  if (n >= NN) return;
  int r0 = rowptr[n], r1 = rowptr[n + 1];
  float l0 = 0.f, l1 = 0.f, l2 = 0.f, l3 = 0.f;
  float ac0 = 0.f, ac1 = 0.f, ac2 = 0.f, ac3 = 0.f;
  int j = r0;
  for (; j + 4 <= r1; j += 4) {
    int s0 = colrow[j].x, s1 = colrow[j+1].x, s2 = colrow[j+2].x, s3 = colrow[j+3].x;
    float4 p0 = pe4[j], p1 = pe4[j+1], p2 = pe4[j+2], p3 = pe4[j+3];
    float v0 = __half2float(h1h[(size_t)s0 * 64 + lane]);
    float v1 = __half2float(h1h[(size_t)s1 * 64 + lane]);
    float v2 = __half2float(h1h[(size_t)s2 * 64 + lane]);
    float v3 = __half2float(h1h[(size_t)s3 * 64 + lane]);
    l0 += (p0.x + p1.x) + (p2.x + p3.x);
    l1 += (p0.y + p1.y) + (p2.y + p3.y);
    l2 += (p0.z + p1.z) + (p2.z + p3.z);
    l3 += (p0.w + p1.w) + (p2.w + p3.w);
    ac0 += p0.x * v0 + p1.x * v1 + p2.x * v2 + p3.x * v3;
    ac1 += p0.y * v0 + p1.y * v1 + p2.y * v2 + p3.y * v3;
    ac2 += p0.z * v0 + p1.z * v1 + p2.z * v2 + p3.z * v3;
    ac3 += p0.w * v0 + p1.w * v1 + p2.w * v2 + p3.w * v3;
  }
  for (; j < r1; j++) {
    int s = colrow[j].x;
    float4 p = pe4[j];
    float v = __half2float(h1h[(size_t)s * 64 + lane]);
    l0 += p.x; l1 += p.y; l2 += p.z; l3 += p.w;
    ac0 += p.x * v; ac1 += p.y * v; ac2 += p.z * v; ac3 += p.w * v;
  }
  __half* zr = z + (size_t)n * 256;
  zr[lane]       = __float2half(ac0 / (4.f * (l0 + 1e-16f)));
  zr[64 + lane]  = __float2half(ac1 / (4.f * (l1 + 1e-16f)));
  zr[128 + lane] = __float2half(ac2 / (4.f * (l2 + 1e-16f)));
  zr[192 + lane] = __float2half(ac3 / (4.f * (l3 + 1e-16f)));
}

// h2[n,d] = relu(bn2( z'[n,:] @ W2r[:,d] + b2[d] ))
__global__ void __launch_bounds__(256) k_zproj(const __half* __restrict__ z,
                      const float* __restrict__ W2r, const float* __restrict__ b2,
                      const float* __restrict__ g2, const float* __restrict__ bt2,
                      float* __restrict__ h2, __half* __restrict__ h2h){
  __shared__ float sz[4][256];
  __shared__ float sacc[4][4][64];
  int tid = threadIdx.x;
  int w = tid >> 6, d = tid & 63;
  float wreg[64];
  #pragma unroll
  for (int i = 0; i < 64; i++) wreg[i] = W2r[(w * 64 + i) * 64 + d];
  float gd = g2[d] * rsqrtf(1.f + 1e-5f), btd = bt2[d], bd = b2[d];
  int n0base = blockIdx.x * 64;
  for (int r = 0; r < 16; r++) {
    int n0 = n0base + r * 4;
    for (int i = tid; i < 512; i += 256) {
      int m = i >> 7, c = (i & 127) * 2;
      int n = n0 + m;
      if (n < NN) {
        __half2 hv = *(const __half2*)(z + (size_t)n * 256 + c);
        float2 f = __half22float2(hv);
        sz[m][c] = f.x; sz[m][c + 1] = f.y;
      } else { sz[m][c] = 0.f; sz[m][c + 1] = 0.f; }
    }
    __syncthreads();
    #pragma unroll
    for (int m = 0; m < 4; m++) {
      float acc = 0.f;
      #pragma unroll
      for (int i = 0; i < 64; i++) acc += sz[m][w * 64 + i] * wreg[i];
      sacc[m][w][d] = acc;
    }
    __syncthreads();
    int n = n0 + w;
    if (n < NN) {
      float rr = sacc[w][0][d] + sacc[w][1][d] + sacc[w][2][d] + sacc[w][3][d] + bd;
      rr = rr * gd + btd;
      rr = fmaxf(rr, 0.f);
      h2[(size_t)n * 64 + d] = rr;
      h2h[(size_t)n * 64 + d] = __float2half(rr);
    }
    __syncthreads();
  }
}

// FUSED agg3 + sage3: wave per node. Lane d gathers agg3[d]; shuffle-broadcast matmul
// with K split across the two 32-lane halves; lanes 0..31 finalize output j = lane.
__global__ void __launch_bounds__(256) k_sage3f(
    const int* __restrict__ rowptr, const int2* __restrict__ colrow,
    const float* __restrict__ x, const float* __restrict__ h2,
    const __half* __restrict__ h2h, const int* __restrict__ count,
    const float* __restrict__ Wl3, const float* __restrict__ Wr3,
    const float* __restrict__ b3, const float* __restrict__ g3,
    const float* __restrict__ bt3, const float* __restrict__ Wskip,
    const float* __restrict__ bskip, float* __restrict__ h3){
  __shared__ float sWl[HID * CH], sWr[HID * CH], sWs[IN_F * CH];
  for (int i = threadIdx.x; i < HID * CH; i += 256) { sWl[i] = Wl3[i]; sWr[i] = Wr3[i]; }
  for (int i = threadIdx.x; i < IN_F * CH; i += 256) sWs[i] = Wskip[i];
  __syncthreads();
  int wid = threadIdx.x >> 6, lane = threadIdx.x & 63;
  int n = blockIdx.x * 4 + wid;
  int nc = n < NN ? n : NN - 1;
  int r0 = rowptr[nc], r1 = rowptr[nc + 1];
  float aval = 0.f;
  int j = r0;
  for (; j + 4 <= r1; j += 4) {
    int s0 = colrow[j].x, s1 = colrow[j+1].x, s2 = colrow[j+2].x, s3 = colrow[j+3].x;
    float v0 = __half2float(h2h[(size_t)s0 * 64 + lane]);
    float v1 = __half2float(h2h[(size_t)s1 * 64 + lane]);
    float v2 = __half2float(h2h[(size_t)s2 * 64 + lane]);
    float v3 = __half2float(h2h[(size_t)s3 * 64 + lane]);
    aval += (v0 + v1) + (v2 + v3);
  }
  for (; j < r1; j++) aval += __half2float(h2h[(size_t)colrow[j].x * 64 + lane]);
  float inv = 1.f / fmaxf((float)count[nc], 1.f);
  aval *= inv;
  float hval = h2[(size_t)nc * 64 + lane];
  int jj = lane & 31;
  int kbase = (lane >> 5) * 32;
  float c = 0.f;
  #pragma unroll
  for (int k0 = 0; k0 < 32; k0++) {
    int k = kbase + k0;
    c += __shfl(aval, k) * sWl[k * CH + jj] + __shfl(hval, k) * sWr[k * CH + jj];
  }
  c += __shfl_xor(c, 32);
  if (lane < 32 && n < NN) {
    float acc = c + b3[jj];
    acc = acc * (g3[jj] * rsqrtf(1.f + 1e-5f)) + bt3[jj];
    acc = fmaxf(acc, 0.f);
    float idn = bskip[jj];
    const float* xr = x + (size_t)n * IN_F;
    #pragma unroll
    for (int k = 0; k < IN_F; k++) idn += xr[k] * sWs[k * CH + jj];
    h3[(size_t)n * CH + jj] = acc + idn;
  }
}

// classifier: 64-thread blocks, LDS-staged h3 tile (pad 33), dual accumulators.
__global__ void __launch_bounds__(64) k_cls(const float* __restrict__ h3,
                      const float* __restrict__ Wc1, const float* __restrict__ bc1,
                      const float* __restrict__ Wc2, const float* __restrict__ bc2,
                      float* __restrict__ out){
  __shared__ float sW1[C1 * C1], sW2[C1 * OUTC], sb1[C1], sb2[OUTC];
  __shared__ float sh3[64][CH + 1];
  int tid = threadIdx.x;
  int n0 = blockIdx.x * 64;
  for (int i = tid; i < C1 * C1; i += 64) sW1[i] = Wc1[i];
  if (tid < C1 * OUTC) sW2[tid] = Wc2[tid];
  if (tid < C1) sb1[tid] = bc1[tid];
  if (tid < OUTC) sb2[tid] = bc2[tid];
  for (int i = tid; i < 64 * CH; i += 64) {
    int m = i >> 5, c = i & 31;
    int n = n0 + m;
    sh3[m][c] = (n < NN) ? h3[(size_t)n * CH + c] : 0.f;
  }
  __syncthreads();
  int n = n0 + tid;
  if (n >= NN) return;
  float hrow[CH];
  #pragma unroll
  for (int j = 0; j < CH; j++) hrow[j] = sh3[tid][j];
  float l0 = sb2[0], l1 = sb2[1];
  #pragma unroll
  for (int i = 0; i < C1; i++) {
    float c0 = sb1[i], c1 = 0.f;
    #pragma unroll
    for (int j = 0; j < CH; j += 2) {
      c0 += hrow[j] * sW1[j * C1 + i];
      c1 += hrow[j + 1] * sW1[(j + 1) * C1 + i];
    }
    float c = fmaxf(c0 + c1, 0.f);
    l0 += c * sW2[i * OUTC + 0];
    l1 += c * sW2[i * OUTC + 1];
  }
  float mx = fmaxf(l0, l1);
  float lse = mx + logf(expf(l0 - mx) + expf(l1 - mx));
  out[n * OUTC + 0] = l0 - lse;
  out[n * OUTC + 1] = l1 - lse;
}

extern "C" void kernel_launch(void* const* d_in, const int* in_sizes, int n_in,
                              void* d_out, int out_size, void* d_ws, size_t ws_size,
                              hipStream_t stream) {
  const float* x       = (const float*)d_in[0];
  const int*   ei      = (const int*)d_in[1];
  const float* Wl1     = (const float*)d_in[2];
  const float* Wr1     = (const float*)d_in[3];
  const float* b1      = (const float*)d_in[4];
  const float* g1      = (const float*)d_in[5];
  const float* bt1     = (const float*)d_in[6];
  const float* W2      = (const float*)d_in[7];
  const float* att_src = (const float*)d_in[8];
  const float* att_dst = (const float*)d_in[9];
  const float* b2      = (const float*)d_in[10];
  const float* g2      = (const float*)d_in[11];
  const float* bt2     = (const float*)d_in[12];
  const float* Wl3     = (const float*)d_in[13];
  const float* Wr3     = (const float*)d_in[14];
  const float* b3      = (const float*)d_in[15];
  const float* g3      = (const float*)d_in[16];
  const float* bt3     = (const float*)d_in[17];
  const float* Wskip   = (const float*)d_in[18];
  const float* bskip   = (const float*)d_in[19];
  const float* Wc1     = (const float*)d_in[20];
  const float* bc1     = (const float*)d_in[21];
  const float* Wc2     = (const float*)d_in[22];
  const float* bc2     = (const float*)d_in[23];
  float* out = (float*)d_out;

  const int* src = ei;
  const int* dst = ei + NE;

  float* ws = (float*)d_ws;
  size_t off = 0;
  auto alloc = [&](size_t nf) { size_t o = off; off += (nf + 63) & ~(size_t)63; return o; };
  // zero region (ints): count, cnt2 — contiguous, memset'd
  size_t o_count = alloc(NN);
  size_t o_cnt2  = alloc(NN);
  size_t zero_elems = off;
  size_t o_rowptr = alloc(NN + 1);
  size_t o_bsum   = alloc(256);
  size_t o_bsumex = alloc(256);
  size_t o_colrow = alloc((size_t)NE * 2);
  size_t o_pe     = alloc((size_t)NE * 4);
  size_t o_xh     = alloc((size_t)NN * IN_F / 2 + 64);      // fp16
  size_t o_aggx   = alloc((size_t)NN * IN_F);
  size_t o_h1h    = alloc((size_t)NN * HID / 2 + 64);       // fp16
  size_t o_as     = alloc((size_t)NN * HEADS);
  size_t o_ad     = alloc((size_t)NN * HEADS);
  size_t o_was    = alloc(256);
  size_t o_wad    = alloc(256);
  size_t o_w2r    = alloc(256 * 64);
  size_t o_z      = alloc((size_t)NN * 256 / 2 + 64);       // fp16
  size_t o_h2     = alloc((size_t)NN * HID);
  size_t o_h2h    = alloc((size_t)NN * HID / 2 + 64);       // fp16
  size_t o_h3     = alloc((size_t)NN * CH);
  (void)ws_size; (void)in_sizes; (void)n_in; (void)out_size;

  int* count    = (int*)(ws + o_count);
  int* cnt2     = (int*)(ws + o_cnt2);
  int* rowptr   = (int*)(ws + o_rowptr);
  int* bsum     = (int*)(ws + o_bsum);
  int* bsumex   = (int*)(ws + o_bsumex);
  int2* colrow  = (int2*)(ws + o_colrow);
  float* pe     = ws + o_pe;
  __half* xh    = (__half*)(ws + o_xh);
  float* aggx   = ws + o_aggx;
  __half* h1h   = (__half*)(ws + o_h1h);
  float* a_s    = ws + o_as;
  float* a_d    = ws + o_ad;
  float* was    = ws + o_was;
  float* wad    = ws + o_wad;
  float* W2r    = ws + o_w2r;
  __half* z     = (__half*)(ws + o_z);
  float* h2     = ws + o_h2;
  __half* h2h   = (__half*)(ws + o_h2h);
  float* h3     = ws + o_h3;

  auto nb = [](long long n) { return (int)((n + 255) / 256); };
  const int nscan = nb(NN);  // 196

  hipMemsetAsync(ws, 0, zero_elems * sizeof(int), stream);
  k_count<<<nb(NE), 256, 0, stream>>>(dst, count);
  k_scan_block<<<nscan, 256, 0, stream>>>(count, rowptr, bsum, NN);
  k_scan_block<<<1, 256, 0, stream>>>(bsum, bsumex, nullptr, nscan);
  k_add_off<<<nscan, 256, 0, stream>>>(rowptr, bsumex, NN);
  k_scatter<<<nb(NE), 256, 0, stream>>>(src, dst, rowptr, cnt2, colrow);
  k_prep<<<nb((long long)NN * IN_F), 256, 0, stream>>>(x, W2, att_src, att_dst, xh, was, wad, W2r);
  k_aggx_gather<<<nb((long long)NN * IN_F), 256, 0, stream>>>(rowptr, colrow, xh, aggx);
  k_sage1<<<nb((long long)NN * HID), 256, 0, stream>>>(x, aggx, count, Wl1, Wr1, b1, g1, bt1,
                                                       was, wad, h1h, a_s, a_d);
  k_edgep<<<nb(NE), 256, 0, stream>>>(colrow, (const float4*)a_s, (const float4*)a_d, (float4*)pe);
  k_gat_fused<<<nb((long long)NN * 64), 256, 0, stream>>>(rowptr, colrow, (const float4*)pe, h1h, z);
  k_zproj<<<(NN + 63) / 64, 256, 0, stream>>>(z, W2r, b2, g2, bt2, h2, h2h);
  k_sage3f<<<(NN + 3) / 4, 256, 0, stream>>>(rowptr, colrow, x, h2, h2h, count,
                                             Wl3, Wr3, b3, g3, bt3, Wskip, bskip, h3);
  k_cls<<<(NN + 63) / 64, 64, 0, stream>>>(h3, Wc1, bc1, Wc2, bc2, out);
}

// Round 6
// 321.234 us; speedup vs baseline: 6.4659x; 1.0675x over previous
//
#include <hip/hip_runtime.h>
#include <hip/hip_fp16.h>
#include <math.h>

#define NN 50000
#define NE 800000
#define IN_F 20
#define HID 64
#define HEADS 4
#define HD 64
#define CH 32      // hidden//2
#define C1 32      // classifier hidden
#define OUTC 2

// count[d] = in-degree
__global__ void k_count(const int* __restrict__ dst, int* __restrict__ count){
  int e = blockIdx.x * 256 + threadIdx.x;
  if (e < NE) atomicAdd(&count[dst[e]], 1);
}

// per-block exclusive scan (256 elems); block sums out
__global__ void k_scan_block(const int* __restrict__ in, int* __restrict__ out,
                             int* __restrict__ bsum, int n){
  __shared__ int tmp[256];
  int g = blockIdx.x * 256 + threadIdx.x;
  int v = (g < n) ? in[g] : 0;
  tmp[threadIdx.x] = v;
  __syncthreads();
  for (int o = 1; o < 256; o <<= 1) {
    int t = ((int)threadIdx.x >= o) ? tmp[threadIdx.x - o] : 0;
    __syncthreads();
    tmp[threadIdx.x] += t;
    __syncthreads();
  }
  if (g < n) out[g] = tmp[threadIdx.x] - v;   // exclusive
  if (bsum && threadIdx.x == 255) bsum[blockIdx.x] = tmp[255];
}

__global__ void k_add_off(int* __restrict__ rowptr, const int* __restrict__ bsum_ex, int n){
  int g = blockIdx.x * 256 + threadIdx.x;
  if (g < n) rowptr[g] += bsum_ex[g >> 8];
  if (g == 0) rowptr[NN] = NE;
}

// colrow[rowptr[d] + slot] = (src[e], d)  — single 8B scattered store per edge
__global__ void k_scatter(const int* __restrict__ src, const int* __restrict__ dst,
                          const int* __restrict__ rowptr, int* __restrict__ cnt2,
                          int2* __restrict__ colrow){
  int e = blockIdx.x * 256 + threadIdx.x;
  if (e >= NE) return;
  int d = dst[e];
  int p = rowptr[d] + atomicAdd(&cnt2[d], 1);
  colrow[p] = make_int2(src[e], d);
}

// fused prep: xh = fp16(x); was/wad folded attention vectors; W2r reordered
__global__ void k_prep(const float* __restrict__ x, const float* __restrict__ W2,
                       const float* __restrict__ att_src, const float* __restrict__ att_dst,
                       __half* __restrict__ xh, float* __restrict__ was,
                       float* __restrict__ wad, float* __restrict__ W2r){
  int i = blockIdx.x * 256 + threadIdx.x;
  if (i < NN * IN_F) xh[i] = __float2half(x[i]);
  if (i < 256 * 64) {
    int hk = i >> 6, d = i & 63;
    int h = hk >> 6, k = hk & 63;
    W2r[i] = W2[k * 256 + h * 64 + d];
  }
  if (i < 256) {
    int h = i >> 6, k = i & 63;
    float s = 0.f, dd = 0.f;
    for (int d = 0; d < 64; d++) {
      float w = W2[k * 256 + h * 64 + d];
      s  += w * att_src[h * 64 + d];
      dd += w * att_dst[h * 64 + d];
    }
    was[i] = s; wad[i] = dd;
  }
}

// aggx[n,k] = sum over incoming edges of xh[src,k]; exact thread per (n, k<20)
__global__ void k_aggx_gather(const int* __restrict__ rowptr, const int2* __restrict__ colrow,
                              const __half* __restrict__ xh, float* __restrict__ aggx){
  int idx = blockIdx.x * 256 + threadIdx.x;
  if (idx >= NN * IN_F) return;
  int n = idx / IN_F, k = idx - n * IN_F;
  int r0 = rowptr[n], r1 = rowptr[n + 1];
  float acc = 0.f;
  int j = r0;
  for (; j + 4 <= r1; j += 4) {
    int s0 = colrow[j].x, s1 = colrow[j+1].x, s2 = colrow[j+2].x, s3 = colrow[j+3].x;
    float v0 = __half2float(xh[s0 * IN_F + k]);
    float v1 = __half2float(xh[s1 * IN_F + k]);
    float v2 = __half2float(xh[s2 * IN_F + k]);
    float v3 = __half2float(xh[s3 * IN_F + k]);
    acc += (v0 + v1) + (v2 + v3);
  }
  for (; j < r1; j++) acc += __half2float(xh[colrow[j].x * IN_F + k]);
  aggx[idx] = acc;
}

// h1 = relu(bn1(aggx/deg @ Wl1 + x @ Wr1 + b1)); writes fp16 h1h + attention logits
__global__ void k_sage1(const float* __restrict__ x, const float* __restrict__ aggx,
                        const int* __restrict__ count,
                        const float* __restrict__ Wl, const float* __restrict__ Wr,
                        const float* __restrict__ b, const float* __restrict__ g,
                        const float* __restrict__ bt,
                        const float* __restrict__ was, const float* __restrict__ wad,
                        __half* __restrict__ h1h, float* __restrict__ a_s,
                        float* __restrict__ a_d){
  __shared__ float sWl[IN_F * HID], sWr[IN_F * HID], sWas[256], sWad[256];
  for (int i = threadIdx.x; i < IN_F * HID; i += 256) { sWl[i] = Wl[i]; sWr[i] = Wr[i]; }
  { int i = threadIdx.x; sWas[i] = was[i]; sWad[i] = wad[i]; }
  __syncthreads();
  int idx = blockIdx.x * 256 + threadIdx.x;
  if (idx >= NN * HID) return;
  int n = idx >> 6, j = idx & 63;
  float inv = 1.f / fmaxf((float)count[n], 1.f);
  const float* xr = x + n * IN_F;
  const float* ar = aggx + n * IN_F;
  float acc = b[j];
  #pragma unroll
  for (int k = 0; k < IN_F; k++)
    acc += (ar[k] * inv) * sWl[k * HID + j] + xr[k] * sWr[k * HID + j];
  acc = acc * (g[j] * rsqrtf(1.f + 1e-5f)) + bt[j];
  acc = fmaxf(acc, 0.f);
  h1h[idx] = __float2half(acc);
  #pragma unroll
  for (int h = 0; h < HEADS; h++) {
    float vs = acc * sWas[h * 64 + j];
    float vd = acc * sWad[h * 64 + j];
    #pragma unroll
    for (int o = 32; o > 0; o >>= 1) { vs += __shfl_down(vs, o); vd += __shfl_down(vd, o); }
    if (j == 0) { a_s[n * 4 + h] = vs; a_d[n * 4 + h] = vd; }
  }
}

// edge-parallel: pe[j] = exp(leaky(a_s[col[j]] + a_d[row[j]])) per head (CSR slot order)
__global__ void k_edgep(const int2* __restrict__ colrow,
                        const float4* __restrict__ a_s4, const float4* __restrict__ a_d4,
                        float4* __restrict__ pe4){
  int j = blockIdx.x * 256 + threadIdx.x;
  if (j >= NE) return;
  int2 cr = colrow[j];
  float4 as = a_s4[cr.x];
  float4 ad = a_d4[cr.y];
  float e0 = as.x + ad.x; e0 = e0 >= 0.f ? e0 : 0.2f * e0;
  float e1 = as.y + ad.y; e1 = e1 >= 0.f ? e1 : 0.2f * e1;
  float e2 = as.z + ad.z; e2 = e2 >= 0.f ? e2 : 0.2f * e2;
  float e3 = as.w + ad.w; e3 = e3 >= 0.f ? e3 : 0.2f * e3;
  pe4[j] = make_float4(__expf(e0), __expf(e1), __expf(e2), __expf(e3));
}

// Fused GAT: wave per node. Lanes split into 2 groups of 32 (group = even/odd edge);
// each lane covers 2 features via half2. Unroll 4 -> 8 row loads in flight per wave.
__global__ void k_gat_fused(const int* __restrict__ rowptr, const int2* __restrict__ colrow,
                            const float4* __restrict__ pe4,
                            const __half* __restrict__ h1h, __half* __restrict__ z){
  int wid = threadIdx.x >> 6;
  int lane = threadIdx.x & 63;
  int grp = lane >> 5;            // 0: even edges, 1: odd edges
  int idx = lane & 31;            // feature pair index (features 2*idx, 2*idx+1)
  int n = blockIdx.x * 4 + wid;
  if (n >= NN) return;
  int r0 = rowptr[n], r1 = rowptr[n + 1];
  float l0 = 0.f, l1 = 0.f, l2 = 0.f, l3 = 0.f;
  float2 ac0 = {0,0}, ac1 = {0,0}, ac2 = {0,0}, ac3 = {0,0};
  int base = r0;
  for (; base + 8 <= r1; base += 8) {
    int j0 = base + grp, j1 = base + 2 + grp, j2 = base + 4 + grp, j3 = base + 6 + grp;
    int s0 = colrow[j0].x, s1 = colrow[j1].x, s2 = colrow[j2].x, s3 = colrow[j3].x;
    float4 p0 = pe4[j0], p1 = pe4[j1], p2 = pe4[j2], p3 = pe4[j3];
    float2 v0 = __half22float2(*(const __half2*)(h1h + (size_t)s0 * 64 + 2 * idx));
    float2 v1 = __half22float2(*(const __half2*)(h1h + (size_t)s1 * 64 + 2 * idx));
    float2 v2 = __half22float2(*(const __half2*)(h1h + (size_t)s2 * 64 + 2 * idx));
    float2 v3 = __half22float2(*(const __half2*)(h1h + (size_t)s3 * 64 + 2 * idx));
    l0 += (p0.x + p1.x) + (p2.x + p3.x);
    l1 += (p0.y + p1.y) + (p2.y + p3.y);
    l2 += (p0.z + p1.z) + (p2.z + p3.z);
    l3 += (p0.w + p1.w) + (p2.w + p3.w);
    ac0.x += p0.x*v0.x + p1.x*v1.x + p2.x*v2.x + p3.x*v3.x;
    ac0.y += p0.x*v0.y + p1.x*v1.y + p2.x*v2.y + p3.x*v3.y;
    ac1.x += p0.y*v0.x + p1.y*v1.x + p2.y*v2.x + p3.y*v3.x;
    ac1.y += p0.y*v0.y + p1.y*v1.y + p2.y*v2.y + p3.y*v3.y;
    ac2.x += p0.z*v0.x + p1.z*v1.x + p2.z*v2.x + p3.z*v3.x;
    ac2.y += p0.z*v0.y + p1.z*v1.y + p2.z*v2.y + p3.z*v3.y;
    ac3.x += p0.w*v0.x + p1.w*v1.x + p2.w*v2.x + p3.w*v3.x;
    ac3.y += p0.w*v0.y + p1.w*v1.y + p2.w*v2.y + p3.w*v3.y;
  }
  for (int j = base + grp; j < r1; j += 2) {
    int s = colrow[j].x;
    float4 p = pe4[j];
    float2 v = __half22float2(*(const __half2*)(h1h + (size_t)s * 64 + 2 * idx));
    l0 += p.x; l1 += p.y; l2 += p.z; l3 += p.w;
    ac0.x += p.x*v.x; ac0.y += p.x*v.y;
    ac1.x += p.y*v.x; ac1.y += p.y*v.y;
    ac2.x += p.z*v.x; ac2.y += p.z*v.y;
    ac3.x += p.w*v.x; ac3.y += p.w*v.y;
  }
  // combine the two edge-groups
  l0 += __shfl_xor(l0, 32); l1 += __shfl_xor(l1, 32);
  l2 += __shfl_xor(l2, 32); l3 += __shfl_xor(l3, 32);
  ac0.x += __shfl_xor(ac0.x, 32); ac0.y += __shfl_xor(ac0.y, 32);
  ac1.x += __shfl_xor(ac1.x, 32); ac1.y += __shfl_xor(ac1.y, 32);
  ac2.x += __shfl_xor(ac2.x, 32); ac2.y += __shfl_xor(ac2.y, 32);
  ac3.x += __shfl_xor(ac3.x, 32); ac3.y += __shfl_xor(ac3.y, 32);
  if (grp == 0) {
    float i0 = 1.f / (4.f * (l0 + 1e-16f));
    float i1 = 1.f / (4.f * (l1 + 1e-16f));
    float i2 = 1.f / (4.f * (l2 + 1e-16f));
    float i3 = 1.f / (4.f * (l3 + 1e-16f));
    __half* zr = z + (size_t)n * 256;
    *(__half2*)(zr +       2 * idx) = __floats2half2_rn(ac0.x * i0, ac0.y * i0);
    *(__half2*)(zr +  64 + 2 * idx) = __floats2half2_rn(ac1.x * i1, ac1.y * i1);
    *(__half2*)(zr + 128 + 2 * idx) = __floats2half2_rn(ac2.x * i2, ac2.y * i2);
    *(__half2*)(zr + 192 + 2 * idx) = __floats2half2_rn(ac3.x * i3, ac3.y * i3);
  }
}

// h2[n,d] = relu(bn2( z'[n,:] @ W2r[:,d] + b2[d] ))
__global__ void __launch_bounds__(256) k_zproj(const __half* __restrict__ z,
                      const float* __restrict__ W2r, const float* __restrict__ b2,
                      const float* __restrict__ g2, const float* __restrict__ bt2,
                      float* __restrict__ h2, __half* __restrict__ h2h){
  __shared__ float sz[4][256];
  __shared__ float sacc[4][4][64];
  int tid = threadIdx.x;
  int w = tid >> 6, d = tid & 63;
  float wreg[64];
  #pragma unroll
  for (int i = 0; i < 64; i++) wreg[i] = W2r[(w * 64 + i) * 64 + d];
  float gd = g2[d] * rsqrtf(1.f + 1e-5f), btd = bt2[d], bd = b2[d];
  int n0base = blockIdx.x * 64;
  for (int r = 0; r < 16; r++) {
    int n0 = n0base + r * 4;
    for (int i = tid; i < 512; i += 256) {
      int m = i >> 7, c = (i & 127) * 2;
      int n = n0 + m;
      if (n < NN) {
        __half2 hv = *(const __half2*)(z + (size_t)n * 256 + c);
        float2 f = __half22float2(hv);
        sz[m][c] = f.x; sz[m][c + 1] = f.y;
      } else { sz[m][c] = 0.f; sz[m][c + 1] = 0.f; }
    }
    __syncthreads();
    #pragma unroll
    for (int m = 0; m < 4; m++) {
      float acc = 0.f;
      #pragma unroll
      for (int i = 0; i < 64; i++) acc += sz[m][w * 64 + i] * wreg[i];
      sacc[m][w][d] = acc;
    }
    __syncthreads();
    int n = n0 + w;
    if (n < NN) {
      float rr = sacc[w][0][d] + sacc[w][1][d] + sacc[w][2][d] + sacc[w][3][d] + bd;
      rr = rr * gd + btd;
      rr = fmaxf(rr, 0.f);
      h2[(size_t)n * 64 + d] = rr;
      h2h[(size_t)n * 64 + d] = __float2half(rr);
    }
    __syncthreads();
  }
}

// FUSED agg3 + sage3: wave per node gathers (half2 lanes, 2-edge groups) into LDS,
// then block-wide LDS matmul phase (no long shuffle chains).
__global__ void __launch_bounds__(256) k_sage3f(
    const int* __restrict__ rowptr, const int2* __restrict__ colrow,
    const float* __restrict__ x, const float* __restrict__ h2,
    const __half* __restrict__ h2h, const int* __restrict__ count,
    const float* __restrict__ Wl3, const float* __restrict__ Wr3,
    const float* __restrict__ b3, const float* __restrict__ g3,
    const float* __restrict__ bt3, const float* __restrict__ Wskip,
    const float* __restrict__ bskip, float* __restrict__ h3){
  __shared__ float sWl[HID * CH], sWr[HID * CH], sWs[IN_F * CH];
  __shared__ float sA[4][HID], sH[4][HID];
  for (int i = threadIdx.x; i < HID * CH; i += 256) { sWl[i] = Wl3[i]; sWr[i] = Wr3[i]; }
  for (int i = threadIdx.x; i < IN_F * CH; i += 256) sWs[i] = Wskip[i];
  int wid = threadIdx.x >> 6, lane = threadIdx.x & 63;
  int grp = lane >> 5, idx = lane & 31;
  int n = blockIdx.x * 4 + wid;
  int nc = n < NN ? n : NN - 1;
  int r0 = rowptr[nc], r1 = rowptr[nc + 1];
  float2 av = {0, 0};
  int base = r0;
  for (; base + 8 <= r1; base += 8) {
    int j0 = base + grp, j1 = base + 2 + grp, j2 = base + 4 + grp, j3 = base + 6 + grp;
    int s0 = colrow[j0].x, s1 = colrow[j1].x, s2 = colrow[j2].x, s3 = colrow[j3].x;
    float2 v0 = __half22float2(*(const __half2*)(h2h + (size_t)s0 * 64 + 2 * idx));
    float2 v1 = __half22float2(*(const __half2*)(h2h + (size_t)s1 * 64 + 2 * idx));
    float2 v2 = __half22float2(*(const __half2*)(h2h + (size_t)s2 * 64 + 2 * idx));
    float2 v3 = __half22float2(*(const __half2*)(h2h + (size_t)s3 * 64 + 2 * idx));
    av.x += (v0.x + v1.x) + (v2.x + v3.x);
    av.y += (v0.y + v1.y) + (v2.y + v3.y);
  }
  for (int j = base + grp; j < r1; j += 2) {
    float2 v = __half22float2(*(const __half2*)(h2h + (size_t)colrow[j].x * 64 + 2 * idx));
    av.x += v.x; av.y += v.y;
  }
  av.x += __shfl_xor(av.x, 32);
  av.y += __shfl_xor(av.y, 32);
  float inv = 1.f / fmaxf((float)count[nc], 1.f);
  if (grp == 0) { sA[wid][2 * idx] = av.x * inv; sA[wid][2 * idx + 1] = av.y * inv; }
  sH[wid][lane] = h2[(size_t)nc * 64 + lane];
  __syncthreads();
  // matmul phase: thread = (m=wid, half=grp, j=idx); K-half per grp
  int kbase = grp * 32;
  float c0 = 0.f, c1 = 0.f;
  #pragma unroll
  for (int k0 = 0; k0 < 32; k0 += 2) {
    int k = kbase + k0;
    c0 += sA[wid][k] * sWl[k * CH + idx] + sH[wid][k] * sWr[k * CH + idx];
    c1 += sA[wid][k+1] * sWl[(k+1) * CH + idx] + sH[wid][k+1] * sWr[(k+1) * CH + idx];
  }
  float c = c0 + c1;
  c += __shfl_xor(c, 32);
  if (grp == 0 && n < NN) {
    float acc = c + b3[idx];
    acc = acc * (g3[idx] * rsqrtf(1.f + 1e-5f)) + bt3[idx];
    acc = fmaxf(acc, 0.f);
    float idn = bskip[idx];
    const float* xr = x + (size_t)n * IN_F;
    #pragma unroll
    for (int k = 0; k < IN_F; k++) idn += xr[k] * sWs[k * CH + idx];
    h3[(size_t)n * CH + idx] = acc + idn;
  }
}

// classifier: 64-thread blocks, LDS-staged h3 tile (pad), dual accumulators.
__global__ void __launch_bounds__(64) k_cls(const float* __restrict__ h3,
                      const float* __restrict__ Wc1, const float* __restrict__ bc1,
                      const float* __restrict__ Wc2, const float* __restrict__ bc2,
                      float* __restrict__ out){
  __shared__ float sW1[C1 * C1], sW2[C1 * OUTC], sb1[C1], sb2[OUTC];
  __shared__ float sh3[64][CH + 1];
  int tid = threadIdx.x;
  int n0 = blockIdx.x * 64;
  for (int i = tid; i < C1 * C1; i += 64) sW1[i] = Wc1[i];
  if (tid < C1 * OUTC) sW2[tid] = Wc2[tid];
  if (tid < C1) sb1[tid] = bc1[tid];
  if (tid < OUTC) sb2[tid] = bc2[tid];
  for (int i = tid; i < 64 * CH; i += 64) {
    int m = i >> 5, c = i & 31;
    int n = n0 + m;
    sh3[m][c] = (n < NN) ? h3[(size_t)n * CH + c] : 0.f;
  }
  __syncthreads();
  int n = n0 + tid;
  if (n >= NN) return;
  float hrow[CH];
  #pragma unroll
  for (int j = 0; j < CH; j++) hrow[j] = sh3[tid][j];
  float l0 = sb2[0], l1 = sb2[1];
  #pragma unroll
  for (int i = 0; i < C1; i++) {
    float c0 = sb1[i], c1 = 0.f;
    #pragma unroll
    for (int j = 0; j < CH; j += 2) {
      c0 += hrow[j] * sW1[j * C1 + i];
      c1 += hrow[j + 1] * sW1[(j + 1) * C1 + i];
    }
    float c = fmaxf(c0 + c1, 0.f);
    l0 += c * sW2[i * OUTC + 0];
    l1 += c * sW2[i * OUTC + 1];
  }
  float mx = fmaxf(l0, l1);
  float lse = mx + logf(expf(l0 - mx) + expf(l1 - mx));
  out[n * OUTC + 0] = l0 - lse;
  out[n * OUTC + 1] = l1 - lse;
}

extern "C" void kernel_launch(void* const* d_in, const int* in_sizes, int n_in,
                              void* d_out, int out_size, void* d_ws, size_t ws_size,
                              hipStream_t stream) {
  const float* x       = (const float*)d_in[0];
  const int*   ei      = (const int*)d_in[1];
  const float* Wl1     = (const float*)d_in[2];
  const float* Wr1     = (const float*)d_in[3];
  const float* b1      = (const float*)d_in[4];
  const float* g1      = (const float*)d_in[5];
  const float* bt1     = (const float*)d_in[6];
  const float* W2      = (const float*)d_in[7];
  const float* att_src = (const float*)d_in[8];
  const float* att_dst = (const float*)d_in[9];
  const float* b2      = (const float*)d_in[10];
  const float* g2      = (const float*)d_in[11];
  const float* bt2     = (const float*)d_in[12];
  const float* Wl3     = (const float*)d_in[13];
  const float* Wr3     = (const float*)d_in[14];
  const float* b3      = (const float*)d_in[15];
  const float* g3      = (const float*)d_in[16];
  const float* bt3     = (const float*)d_in[17];
  const float* Wskip   = (const float*)d_in[18];
  const float* bskip   = (const float*)d_in[19];
  const float* Wc1     = (const float*)d_in[20];
  const float* bc1     = (const float*)d_in[21];
  const float* Wc2     = (const float*)d_in[22];
  const float* bc2     = (const float*)d_in[23];
  float* out = (float*)d_out;

  const int* src = ei;
  const int* dst = ei + NE;

  float* ws = (float*)d_ws;
  size_t off = 0;
  auto alloc = [&](size_t nf) { size_t o = off; off += (nf + 63) & ~(size_t)63; return o; };
  // zero region (ints): count, cnt2 — contiguous, memset'd
  size_t o_count = alloc(NN);
  size_t o_cnt2  = alloc(NN);
  size_t zero_elems = off;
  size_t o_rowptr = alloc(NN + 1);
  size_t o_bsum   = alloc(256);
  size_t o_bsumex = alloc(256);
  size_t o_colrow = alloc((size_t)NE * 2);
  size_t o_pe     = alloc((size_t)NE * 4);
  size_t o_xh     = alloc((size_t)NN * IN_F / 2 + 64);      // fp16
  size_t o_aggx   = alloc((size_t)NN * IN_F);
  size_t o_h1h    = alloc((size_t)NN * HID / 2 + 64);       // fp16
  size_t o_as     = alloc((size_t)NN * HEADS);
  size_t o_ad     = alloc((size_t)NN * HEADS);
  size_t o_was    = alloc(256);
  size_t o_wad    = alloc(256);
  size_t o_w2r    = alloc(256 * 64);
  size_t o_z      = alloc((size_t)NN * 256 / 2 + 64);       // fp16
  size_t o_h2     = alloc((size_t)NN * HID);
  size_t o_h2h    = alloc((size_t)NN * HID / 2 + 64);       // fp16
  size_t o_h3     = alloc((size_t)NN * CH);
  (void)ws_size; (void)in_sizes; (void)n_in; (void)out_size;

  int* count    = (int*)(ws + o_count);
  int* cnt2     = (int*)(ws + o_cnt2);
  int* rowptr   = (int*)(ws + o_rowptr);
  int* bsum     = (int*)(ws + o_bsum);
  int* bsumex   = (int*)(ws + o_bsumex);
  int2* colrow  = (int2*)(ws + o_colrow);
  float* pe     = ws + o_pe;
  __half* xh    = (__half*)(ws + o_xh);
  float* aggx   = ws + o_aggx;
  __half* h1h   = (__half*)(ws + o_h1h);
  float* a_s    = ws + o_as;
  float* a_d    = ws + o_ad;
  float* was    = ws + o_was;
  float* wad    = ws + o_wad;
  float* W2r    = ws + o_w2r;
  __half* z     = (__half*)(ws + o_z);
  float* h2     = ws + o_h2;
  __half* h2h   = (__half*)(ws + o_h2h);
  float* h3     = ws + o_h3;

  auto nb = [](long long n) { return (int)((n + 255) / 256); };
  const int nscan = nb(NN);  // 196

  hipMemsetAsync(ws, 0, zero_elems * sizeof(int), stream);
  k_count<<<nb(NE), 256, 0, stream>>>(dst, count);
  k_scan_block<<<nscan, 256, 0, stream>>>(count, rowptr, bsum, NN);
  k_scan_block<<<1, 256, 0, stream>>>(bsum, bsumex, nullptr, nscan);
  k_add_off<<<nscan, 256, 0, stream>>>(rowptr, bsumex, NN);
  k_scatter<<<nb(NE), 256, 0, stream>>>(src, dst, rowptr, cnt2, colrow);
  k_prep<<<nb((long long)NN * IN_F), 256, 0, stream>>>(x, W2, att_src, att_dst, xh, was, wad, W2r);
  k_aggx_gather<<<nb((long long)NN * IN_F), 256, 0, stream>>>(rowptr, colrow, xh, aggx);
  k_sage1<<<nb((long long)NN * HID), 256, 0, stream>>>(x, aggx, count, Wl1, Wr1, b1, g1, bt1,
                                                       was, wad, h1h, a_s, a_d);
  k_edgep<<<nb(NE), 256, 0, stream>>>(colrow, (const float4*)a_s, (const float4*)a_d, (float4*)pe);
  k_gat_fused<<<nb((long long)NN * 64), 256, 0, stream>>>(rowptr, colrow, (const float4*)pe, h1h, z);
  k_zproj<<<(NN + 63) / 64, 256, 0, stream>>>(z, W2r, b2, g2, bt2, h2, h2h);
  k_sage3f<<<(NN + 3) / 4, 256, 0, stream>>>(rowptr, colrow, x, h2, h2h, count,
                                             Wl3, Wr3, b3, g3, bt3, Wskip, bskip, h3);
  k_cls<<<(NN + 63) / 64, 64, 0, stream>>>(h3, Wc1, bc1, Wc2, bc2, out);
}